// Round 1
// baseline (1370.994 us; speedup 1.0000x reference)
//
#include <hip/hip_runtime.h>
#include <cstddef>

constexpr int NB   = 2;
constexpr int NT   = 8;
constexpr int NP   = 256;
constexpr int DIM  = 1024;
constexpr int NH   = 16;
constexpr int HD   = 64;
constexpr int SEQ  = NT * NP;       // 2048
constexpr int MROW = NB * SEQ;      // 4096
constexpr int N3   = 3 * DIM;       // 3072

// ---------------- K0: RoPE cos/sin table: tab[0:SEQ*32]=cos, [SEQ*32:]=sin ----
__global__ __launch_bounds__(256) void rope_table_kernel(float* __restrict__ tab) {
  int idx = blockIdx.x * 256 + threadIdx.x;
  if (idx >= SEQ * 32) return;
  int l = idx >> 5, i = idx & 31;
  float j = (float)(i & 15);
  // inv_freq = 10000^(-j/16) = 2^(-j*log2(10000)/16)
  float invf = exp2f(-j * (13.287712379549449f / 16.f));
  float pos = (i < 16) ? (float)(l >> 8) : (float)(l & (NP - 1));
  float ang = pos * invf;
  tab[idx]            = cosf(ang);
  tab[SEQ * 32 + idx] = sinf(ang);
}

// ---------------- K1/K4: C[M][N] = A[M][K] * B[N][K]^T  (both K-contiguous) --
// 128x128 tile, BK=16, 256 threads, each thread 8x8 fp32 accumulators.
__global__ __launch_bounds__(256) void gemm_nt_kernel(
    const float* __restrict__ A, const float* __restrict__ B,
    float* __restrict__ C, int Nv, int Kv) {
  __shared__ float As[16][128];   // [k][m]
  __shared__ float Bs[16][128];   // [k][n]
  const int tid = threadIdx.x;
  const int tm = tid >> 4, tn = tid & 15;
  const int bm = blockIdx.y * 128, bn = blockIdx.x * 128;
  const int lrow = tid >> 1;          // 0..127
  const int lc4  = (tid & 1) * 2;     // 0 or 2
  float acc[8][8] = {};
  for (int k0 = 0; k0 < Kv; k0 += 16) {
#pragma unroll
    for (int c = 0; c < 2; ++c) {
      const int kk = (lc4 + c) * 4;
      float4 va = *reinterpret_cast<const float4*>(&A[(size_t)(bm + lrow) * Kv + k0 + kk]);
      As[kk + 0][lrow] = va.x;
      As[kk + 1][lrow] = va.y;
      As[kk + 2][lrow] = va.z;
      As[kk + 3][lrow] = va.w;
      float4 vb = *reinterpret_cast<const float4*>(&B[(size_t)(bn + lrow) * Kv + k0 + kk]);
      Bs[kk + 0][lrow] = vb.x;
      Bs[kk + 1][lrow] = vb.y;
      Bs[kk + 2][lrow] = vb.z;
      Bs[kk + 3][lrow] = vb.w;
    }
    __syncthreads();
#pragma unroll
    for (int k = 0; k < 16; ++k) {
      float a[8], b[8];
      *reinterpret_cast<float4*>(&a[0]) = *reinterpret_cast<const float4*>(&As[k][tm * 8]);
      *reinterpret_cast<float4*>(&a[4]) = *reinterpret_cast<const float4*>(&As[k][tm * 8 + 4]);
      *reinterpret_cast<float4*>(&b[0]) = *reinterpret_cast<const float4*>(&Bs[k][tn * 8]);
      *reinterpret_cast<float4*>(&b[4]) = *reinterpret_cast<const float4*>(&Bs[k][tn * 8 + 4]);
#pragma unroll
      for (int i = 0; i < 8; ++i)
#pragma unroll
        for (int j = 0; j < 8; ++j)
          acc[i][j] = fmaf(a[i], b[j], acc[i][j]);
    }
    __syncthreads();
  }
#pragma unroll
  for (int i = 0; i < 8; ++i) {
    float4 v0 = make_float4(acc[i][0], acc[i][1], acc[i][2], acc[i][3]);
    float4 v1 = make_float4(acc[i][4], acc[i][5], acc[i][6], acc[i][7]);
    size_t off = (size_t)(bm + tm * 8 + i) * Nv + bn + tn * 8;
    *reinterpret_cast<float4*>(&C[off])     = v0;
    *reinterpret_cast<float4*>(&C[off + 4]) = v1;
  }
}

// ---------------- K2: RMSNorm(q,k) + RoPE(q,k) + transpose to (B,H,L,hd) -----
// one block per (b,l); 4 waves; wave handles heads {w, w+4, w+8, w+12}
__global__ __launch_bounds__(256) void qkv_post_kernel(
    const float* __restrict__ qkv, const float* __restrict__ qs,
    const float* __restrict__ ks, const float* __restrict__ tab,
    float* __restrict__ qT, float* __restrict__ kT, float* __restrict__ vT) {
  const int bl = blockIdx.x;                  // b*SEQ + l
  const int b = bl >> 11, l = bl & (SEQ - 1);
  const int wave = threadIdx.x >> 6, lane = threadIdx.x & 63;
  const float* row = qkv + (size_t)bl * N3;
  const float cz  = tab[l * 32 + (lane >> 1)];
  const float sz  = tab[SEQ * 32 + l * 32 + (lane >> 1)];
  const float sgn = (lane & 1) ? sz : -sz;    // even: val*c - p*s ; odd: val*c + p*s
  const float qsc = qs[lane], ksc = ks[lane];
  for (int h = wave; h < NH; h += 4) {
    float vq = row[h * HD + lane];
    float vk = row[DIM + h * HD + lane];
    float vv = row[2 * DIM + h * HD + lane];
    float sq = vq * vq, sk = vk * vk;
#pragma unroll
    for (int off = 32; off > 0; off >>= 1) {
      sq += __shfl_xor(sq, off);
      sk += __shfl_xor(sk, off);
    }
    float nq = vq * rsqrtf(sq * (1.f / HD) + 1e-6f) * qsc;
    float nk = vk * rsqrtf(sk * (1.f / HD) + 1e-6f) * ksc;
    float pq = __shfl_xor(nq, 1);
    float pk = __shfl_xor(nk, 1);
    float oq = nq * cz + pq * sgn;
    float ok = nk * cz + pk * sgn;
    size_t o = ((size_t)(b * NH + h) * SEQ + l) * HD + lane;
    qT[o] = oq;
    kT[o] = ok;
    vT[o] = vv;
  }
}

// ---------------- K3: block-causal flash attention (fp32) --------------------
// grid (SEQ/64, B*H); 64 q-rows per block; k-tiles of 64; frames of 256 so the
// mask is exactly "kb < (frame(qb)+1)*4" -- no per-element masking needed.
__global__ __launch_bounds__(256) void attn_kernel(
    const float* __restrict__ qT, const float* __restrict__ kT,
    const float* __restrict__ vT, float* __restrict__ outp) {
  constexpr float SCALE = 0.125f;  // 64^-0.5
  __shared__ float Qs[64][68];     // [r][d], stride 68 keeps 16B align, <=2-way banks
  __shared__ float Kst[64][68];    // [d][c] (transposed at load)
  __shared__ float Vs[64][68];     // [c][d]
  __shared__ float Ps[64][68];     // [r][c]
  const int qb = blockIdx.x, bh = blockIdx.y;
  const int b = bh >> 4, h = bh & 15;
  const int tid = threadIdx.x;
  const int tr = tid >> 4, tc = tid & 15;
  const float* Qp = qT + ((size_t)bh * SEQ + qb * 64) * HD;
  const float* Kp = kT + (size_t)bh * SEQ * HD;
  const float* Vp = vT + (size_t)bh * SEQ * HD;
  {
    const int row = tid >> 2, c0 = (tid & 3) * 16;
#pragma unroll
    for (int u = 0; u < 4; ++u) {
      float4 v = *reinterpret_cast<const float4*>(&Qp[row * HD + c0 + u * 4]);
      Qs[row][c0 + u * 4 + 0] = v.x * SCALE;
      Qs[row][c0 + u * 4 + 1] = v.y * SCALE;
      Qs[row][c0 + u * 4 + 2] = v.z * SCALE;
      Qs[row][c0 + u * 4 + 3] = v.w * SCALE;
    }
  }
  float m_i[4], l_i[4], o[4][4];
#pragma unroll
  for (int i = 0; i < 4; ++i) {
    m_i[i] = -1e30f; l_i[i] = 0.f;
#pragma unroll
    for (int j = 0; j < 4; ++j) o[i][j] = 0.f;
  }
  const int nkb = ((qb >> 2) + 1) * 4;
  for (int kb = 0; kb < nkb; ++kb) {
    __syncthreads();   // guard Kst/Vs against previous iteration's readers
    {
      const int row = tid >> 2, c0 = (tid & 3) * 16;
      const float* Kt = Kp + (size_t)kb * 64 * HD;
      const float* Vt = Vp + (size_t)kb * 64 * HD;
#pragma unroll
      for (int u = 0; u < 4; ++u) {
        float4 vk = *reinterpret_cast<const float4*>(&Kt[row * HD + c0 + u * 4]);
        Kst[c0 + u * 4 + 0][row] = vk.x;
        Kst[c0 + u * 4 + 1][row] = vk.y;
        Kst[c0 + u * 4 + 2][row] = vk.z;
        Kst[c0 + u * 4 + 3][row] = vk.w;
        float4 vv = *reinterpret_cast<const float4*>(&Vt[row * HD + c0 + u * 4]);
        *reinterpret_cast<float4*>(&Vs[row][c0 + u * 4]) = vv;
      }
    }
    __syncthreads();
    // S = (Q*scale) K^T : thread owns rows tr*4..+4, cols tc*4..+4
    float s[4][4] = {};
#pragma unroll
    for (int d0 = 0; d0 < 64; d0 += 4) {
      float4 a[4], bb[4];
#pragma unroll
      for (int i = 0; i < 4; ++i) a[i] = *reinterpret_cast<const float4*>(&Qs[tr * 4 + i][d0]);
#pragma unroll
      for (int dd = 0; dd < 4; ++dd) bb[dd] = *reinterpret_cast<const float4*>(&Kst[d0 + dd][tc * 4]);
#pragma unroll
      for (int i = 0; i < 4; ++i) {
        s[i][0] += a[i].x * bb[0].x + a[i].y * bb[1].x + a[i].z * bb[2].x + a[i].w * bb[3].x;
        s[i][1] += a[i].x * bb[0].y + a[i].y * bb[1].y + a[i].z * bb[2].y + a[i].w * bb[3].y;
        s[i][2] += a[i].x * bb[0].z + a[i].y * bb[1].z + a[i].z * bb[2].z + a[i].w * bb[3].z;
        s[i][3] += a[i].x * bb[0].w + a[i].y * bb[1].w + a[i].z * bb[2].w + a[i].w * bb[3].w;
      }
    }
    // online softmax (row stats reduced across the 16-lane tc group)
#pragma unroll
    for (int i = 0; i < 4; ++i) {
      float mt = fmaxf(fmaxf(s[i][0], s[i][1]), fmaxf(s[i][2], s[i][3]));
#pragma unroll
      for (int off = 1; off < 16; off <<= 1) mt = fmaxf(mt, __shfl_xor(mt, off));
      float mn = fmaxf(m_i[i], mt);
      float alpha = __expf(m_i[i] - mn);
      float rs = 0.f;
#pragma unroll
      for (int j = 0; j < 4; ++j) { s[i][j] = __expf(s[i][j] - mn); rs += s[i][j]; }
#pragma unroll
      for (int off = 1; off < 16; off <<= 1) rs += __shfl_xor(rs, off);
      l_i[i] = l_i[i] * alpha + rs;
      m_i[i] = mn;
#pragma unroll
      for (int j = 0; j < 4; ++j) o[i][j] *= alpha;
      *reinterpret_cast<float4*>(&Ps[tr * 4 + i][tc * 4]) = make_float4(s[i][0], s[i][1], s[i][2], s[i][3]);
    }
    __syncthreads();
    // O += P V : thread owns rows tr*4..+4, d-cols tc*4..+4
#pragma unroll
    for (int c0 = 0; c0 < 64; c0 += 4) {
      float4 vv[4];
#pragma unroll
      for (int cc = 0; cc < 4; ++cc) vv[cc] = *reinterpret_cast<const float4*>(&Vs[c0 + cc][tc * 4]);
#pragma unroll
      for (int i = 0; i < 4; ++i) {
        float4 p = *reinterpret_cast<const float4*>(&Ps[tr * 4 + i][c0]);
        o[i][0] += p.x * vv[0].x + p.y * vv[1].x + p.z * vv[2].x + p.w * vv[3].x;
        o[i][1] += p.x * vv[0].y + p.y * vv[1].y + p.z * vv[2].y + p.w * vv[3].y;
        o[i][2] += p.x * vv[0].z + p.y * vv[1].z + p.z * vv[2].z + p.w * vv[3].z;
        o[i][3] += p.x * vv[0].w + p.y * vv[1].w + p.z * vv[2].w + p.w * vv[3].w;
      }
    }
  }
  // epilogue: write (B, L, D) layout directly
  const int l0 = qb * 64;
#pragma unroll
  for (int i = 0; i < 4; ++i) {
    float inv = 1.f / l_i[i];
    float4 r = make_float4(o[i][0] * inv, o[i][1] * inv, o[i][2] * inv, o[i][3] * inv);
    *reinterpret_cast<float4*>(&outp[((size_t)b * SEQ + l0 + tr * 4 + i) * DIM + h * HD + tc * 4]) = r;
  }
}

// ---------------- launch -----------------------------------------------------
extern "C" void kernel_launch(void* const* d_in, const int* in_sizes, int n_in,
                              void* d_out, int out_size, void* d_ws, size_t ws_size,
                              hipStream_t stream) {
  const float* x       = (const float*)d_in[0];
  const float* Wqkv    = (const float*)d_in[1];
  const float* Wout    = (const float*)d_in[2];
  const float* q_scale = (const float*)d_in[3];
  const float* k_scale = (const float*)d_in[4];
  float* out = (float*)d_out;

  float* ws  = (float*)d_ws;
  float* qkv = ws;                                        // 4096*3072
  float* qT  = ws + (size_t)MROW * N3;                    // 2*16*2048*64
  float* kT  = qT + (size_t)NB * NH * SEQ * HD;
  float* vT  = kT + (size_t)NB * NH * SEQ * HD;
  float* tab = vT + (size_t)NB * NH * SEQ * HD;           // 2*SEQ*32
  float* attn_out = qkv;                                  // reuse qkv region

  rope_table_kernel<<<dim3(SEQ * 32 / 256), dim3(256), 0, stream>>>(tab);
  gemm_nt_kernel<<<dim3(N3 / 128, MROW / 128), dim3(256), 0, stream>>>(x, Wqkv, qkv, N3, DIM);
  qkv_post_kernel<<<dim3(MROW), dim3(256), 0, stream>>>(qkv, q_scale, k_scale, tab, qT, kT, vT);
  attn_kernel<<<dim3(SEQ / 64, NB * NH), dim3(256), 0, stream>>>(qT, kT, vT, attn_out);
  gemm_nt_kernel<<<dim3(DIM / 128, MROW / 128), dim3(256), 0, stream>>>(attn_out, Wout, out, DIM, DIM);
}

// Round 3
// 485.545 us; speedup vs baseline: 2.8236x; 2.8236x over previous
//
#include <hip/hip_runtime.h>
#include <hip/hip_bf16.h>
#include <cstddef>

typedef unsigned int uint;
typedef unsigned short ushort_t;
typedef __attribute__((ext_vector_type(8))) short bf16x8;
typedef __attribute__((ext_vector_type(4))) float f32x4;

constexpr int NB   = 2;
constexpr int NP   = 256;
constexpr int DIM  = 1024;
constexpr int NH   = 16;
constexpr int HD   = 64;
constexpr int SEQ  = 2048;
constexpr int MROW = NB * SEQ;      // 4096
constexpr int N3   = 3 * DIM;       // 3072
// softmax in base-2: fold hd^-0.5 * log2(e) into q
constexpr float QS = 0.125f * 1.4426950408889634f;

__device__ __forceinline__ ushort_t f2bf(float x) {
  uint u = __builtin_bit_cast(uint, x);
  u = (u + 0x7fff + ((u >> 16) & 1)) >> 16;   // round-to-nearest-even
  return (ushort_t)u;
}
__device__ __forceinline__ uint pack_bf16(float a, float b) {
  return (uint)f2bf(a) | ((uint)f2bf(b) << 16);
}

__device__ __forceinline__ void gload16(const void* g, void* l) {
  __builtin_amdgcn_global_load_lds((const __attribute__((address_space(1))) uint*)g,
                                   (__attribute__((address_space(3))) uint*)l, 16, 0, 0);
}

// ---------------- K0: RoPE cos/sin table ------------------------------------
__global__ __launch_bounds__(256) void rope_table_kernel(float* __restrict__ tab) {
  int idx = blockIdx.x * 256 + threadIdx.x;
  if (idx >= SEQ * 32) return;
  int l = idx >> 5, i = idx & 31;
  float j = (float)(i & 15);
  float invf = exp2f(-j * (13.287712379549449f / 16.f));
  float pos = (i < 16) ? (float)(l >> 8) : (float)(l & (NP - 1));
  float ang = pos * invf;
  tab[idx]            = cosf(ang);
  tab[SEQ * 32 + idx] = sinf(ang);
}

// ---------------- K1/K4: fp32 GEMM  C[M][N] = A[M][K] * B[N][K]^T ------------
__global__ __launch_bounds__(256) void gemm_nt_kernel(
    const float* __restrict__ A, const float* __restrict__ B,
    float* __restrict__ C, int Nv, int Kv) {
  __shared__ float As[16][128];
  __shared__ float Bs[16][128];
  const int tid = threadIdx.x;
  const int tm = tid >> 4, tn = tid & 15;
  const int bm = blockIdx.y * 128, bn = blockIdx.x * 128;
  const int lrow = tid >> 1;
  const int lc4  = (tid & 1) * 2;
  float acc[8][8] = {};
  for (int k0 = 0; k0 < Kv; k0 += 16) {
#pragma unroll
    for (int c = 0; c < 2; ++c) {
      const int kk = (lc4 + c) * 4;
      float4 va = *reinterpret_cast<const float4*>(&A[(size_t)(bm + lrow) * Kv + k0 + kk]);
      As[kk + 0][lrow] = va.x; As[kk + 1][lrow] = va.y;
      As[kk + 2][lrow] = va.z; As[kk + 3][lrow] = va.w;
      float4 vb = *reinterpret_cast<const float4*>(&B[(size_t)(bn + lrow) * Kv + k0 + kk]);
      Bs[kk + 0][lrow] = vb.x; Bs[kk + 1][lrow] = vb.y;
      Bs[kk + 2][lrow] = vb.z; Bs[kk + 3][lrow] = vb.w;
    }
    __syncthreads();
#pragma unroll
    for (int k = 0; k < 16; ++k) {
      float a[8], b[8];
      *reinterpret_cast<float4*>(&a[0]) = *reinterpret_cast<const float4*>(&As[k][tm * 8]);
      *reinterpret_cast<float4*>(&a[4]) = *reinterpret_cast<const float4*>(&As[k][tm * 8 + 4]);
      *reinterpret_cast<float4*>(&b[0]) = *reinterpret_cast<const float4*>(&Bs[k][tn * 8]);
      *reinterpret_cast<float4*>(&b[4]) = *reinterpret_cast<const float4*>(&Bs[k][tn * 8 + 4]);
#pragma unroll
      for (int i = 0; i < 8; ++i)
#pragma unroll
        for (int j = 0; j < 8; ++j)
          acc[i][j] = fmaf(a[i], b[j], acc[i][j]);
    }
    __syncthreads();
  }
#pragma unroll
  for (int i = 0; i < 8; ++i) {
    float4 v0 = make_float4(acc[i][0], acc[i][1], acc[i][2], acc[i][3]);
    float4 v1 = make_float4(acc[i][4], acc[i][5], acc[i][6], acc[i][7]);
    size_t off = (size_t)(bm + tm * 8 + i) * Nv + bn + tn * 8;
    *reinterpret_cast<float4*>(&C[off])     = v0;
    *reinterpret_cast<float4*>(&C[off + 4]) = v1;
  }
}

// ---------------- K2: RMSNorm + RoPE + bf16 cast; qT/kT row-major, vT d-major
// grid: b(2) x ltile(32) x h(16) = 1024 blocks; 256 thr: row=t>>2, dchunk=(t&3)*16
__global__ __launch_bounds__(256) void qkv_post_kernel(
    const float* __restrict__ qkv, const float* __restrict__ qs,
    const float* __restrict__ ksc, const float* __restrict__ tab,
    ushort_t* __restrict__ qT, ushort_t* __restrict__ kT, ushort_t* __restrict__ vT) {
  __shared__ ushort_t vt[64][72];   // transpose staging, stride 72 (144B, 16B-aligned)
  const int bx = blockIdx.x;
  const int h = bx & 15, lt = (bx >> 4) & 31, b = bx >> 9;
  const int t = threadIdx.x, lr = t >> 2, s = t & 3, d0 = s * 16;
  const int lg = lt * 64 + lr;
  const int bh = b * NH + h;
  const float* rowp = qkv + ((size_t)(b * SEQ + lg) * N3) + h * HD + d0;

  float4 q4[4], k4[4], v4[4], qs4[4], ks4[4];
#pragma unroll
  for (int u = 0; u < 4; ++u) {
    q4[u]  = *reinterpret_cast<const float4*>(rowp + u * 4);
    k4[u]  = *reinterpret_cast<const float4*>(rowp + DIM + u * 4);
    v4[u]  = *reinterpret_cast<const float4*>(rowp + 2 * DIM + u * 4);
    qs4[u] = *reinterpret_cast<const float4*>(qs + d0 + u * 4);
    ks4[u] = *reinterpret_cast<const float4*>(ksc + d0 + u * 4);
  }
  const float* vq = reinterpret_cast<const float*>(q4);
  const float* vk = reinterpret_cast<const float*>(k4);
  const float* vv = reinterpret_cast<const float*>(v4);
  const float* sq_ = reinterpret_cast<const float*>(qs4);
  const float* sk_ = reinterpret_cast<const float*>(ks4);

  float sq = 0.f, sk = 0.f;
#pragma unroll
  for (int j = 0; j < 16; ++j) { sq = fmaf(vq[j], vq[j], sq); sk = fmaf(vk[j], vk[j], sk); }
  sq += __shfl_xor(sq, 1); sq += __shfl_xor(sq, 2);
  sk += __shfl_xor(sk, 1); sk += __shfl_xor(sk, 2);
  float rq = rsqrtf(sq * (1.f / HD) + 1e-6f);
  float rk = rsqrtf(sk * (1.f / HD) + 1e-6f);

  float4 c4[2], s4[2];
  const float* tc = tab + (size_t)lg * 32 + s * 8;
  const float* ts = tab + (size_t)SEQ * 32 + (size_t)lg * 32 + s * 8;
  c4[0] = *reinterpret_cast<const float4*>(tc);
  c4[1] = *reinterpret_cast<const float4*>(tc + 4);
  s4[0] = *reinterpret_cast<const float4*>(ts);
  s4[1] = *reinterpret_cast<const float4*>(ts + 4);
  const float* cj = reinterpret_cast<const float*>(c4);
  const float* sj = reinterpret_cast<const float*>(s4);

  uint uq[8], uk[8], uv[8];
#pragma unroll
  for (int j = 0; j < 8; ++j) {
    float qe = vq[2*j] * rq * sq_[2*j], qo = vq[2*j+1] * rq * sq_[2*j+1];
    float ke = vk[2*j] * rk * sk_[2*j], ko = vk[2*j+1] * rk * sk_[2*j+1];
    float c = cj[j], sn = sj[j];
    uq[j] = pack_bf16((qe * c - qo * sn) * QS, (qe * sn + qo * c) * QS);
    uk[j] = pack_bf16(ke * c - ko * sn, ke * sn + ko * c);
    uv[j] = pack_bf16(vv[2*j], vv[2*j+1]);
  }
  ushort_t* qp = qT + ((size_t)bh * SEQ + lg) * HD + d0;
  ushort_t* kp = kT + ((size_t)bh * SEQ + lg) * HD + d0;
  reinterpret_cast<uint4*>(qp)[0] = *reinterpret_cast<uint4*>(&uq[0]);
  reinterpret_cast<uint4*>(qp)[1] = *reinterpret_cast<uint4*>(&uq[4]);
  reinterpret_cast<uint4*>(kp)[0] = *reinterpret_cast<uint4*>(&uk[0]);
  reinterpret_cast<uint4*>(kp)[1] = *reinterpret_cast<uint4*>(&uk[4]);
#pragma unroll
  for (int j = 0; j < 16; ++j)
    vt[d0 + j][lr] = (ushort_t)((j & 1) ? (uv[j >> 1] >> 16) : (uv[j >> 1] & 0xffff));
  __syncthreads();
  const int drow = t >> 2, lc = (t & 3) * 16;
  ushort_t* vp = vT + ((size_t)bh * HD + drow) * SEQ + lt * 64 + lc;
  reinterpret_cast<uint4*>(vp)[0] = *reinterpret_cast<const uint4*>(&vt[drow][lc]);
  reinterpret_cast<uint4*>(vp)[1] = *reinterpret_cast<const uint4*>(&vt[drow][lc + 8]);
}

// ---------------- K3: bf16 MFMA block-causal flash attention -----------------
// grid (16, 32): qb = 15-bx (heavy first), 128 q-rows/block, 4 waves x 32 rows.
// Swapped operands: S^T = K Q^T, O^T = V^T P^T. No online max (scores bounded).
// LDS: dbuf{K 8K, V 8K} x2 + per-wave P 4K = 48KB. XOR swizzle kills row-stride
// bank aliasing; global_load_lds w/ pre-swizzled source (linear LDS dest).
__global__ __launch_bounds__(256) void attn_mfma_kernel(
    const ushort_t* __restrict__ qT, const ushort_t* __restrict__ kT,
    const ushort_t* __restrict__ vT, float* __restrict__ outp) {
  __shared__ __align__(16) char smem[49152];
  const int tid = threadIdx.x;
  const int l  = tid & 63, w4 = tid >> 6;
  const int lm = l & 15, lw = l >> 4, l7 = l & 7, l3 = l >> 3;
  const int bh = blockIdx.y, b = bh >> 4, h = bh & 15;
  const int qb = (int)gridDim.x - 1 - (int)blockIdx.x;
  const int nkb = ((qb >> 1) + 1) * 4;

  // Q fragments (B-operand): lane holds Q[q0+lm][8*lw+i+32*ks]
  bf16x8 qf[2][2];
  const size_t qrow0 = (size_t)bh * SEQ + qb * 128 + w4 * 32;
#pragma unroll
  for (int qm = 0; qm < 2; ++qm)
#pragma unroll
    for (int ks = 0; ks < 2; ++ks)
      qf[qm][ks] = *reinterpret_cast<const bf16x8*>(
          qT + (qrow0 + qm * 16 + lm) * HD + lw * 8 + ks * 32);

  const char* kTb = reinterpret_cast<const char*>(kT + (size_t)bh * SEQ * HD);
  const char* vTb = reinterpret_cast<const char*>(vT + (size_t)bh * HD * SEQ);
  const uint rloc = w4 * 8 + l3;          // staged row (+32 per inst)
  const uint csrc = (uint)((l7 ^ l3) << 4); // pre-swizzled source chunk
  char* Pbase = smem + 32768 + w4 * 4096;

  float l_acc[2] = {0.f, 0.f};
  f32x4 oacc[2][4] = {};

  auto stage = [&](int kb, int buf) {
    const char* sK = kTb + ((size_t)(kb * 64) + rloc) * 128 + csrc;
    const char* sV = vTb + (size_t)rloc * (SEQ * 2) + (size_t)kb * 128 + csrc;
    char* dK = smem + buf * 16384 + w4 * 1024;
    char* dV = dK + 8192;
    gload16(sK, dK);
    gload16(sK + 4096, dK + 4096);
    gload16(sV, dV);
    gload16(sV + (size_t)32 * SEQ * 2, dV + 4096);
  };

  stage(0, 0);
  __syncthreads();

  for (int kb = 0; kb < nkb; ++kb) {
    const int buf = kb & 1;
    if (kb + 1 < nkb) stage(kb + 1, buf ^ 1);
    const char* Kb = smem + buf * 16384;
    const char* Vb = Kb + 8192;

    // S^T = K * Q^T
    f32x4 st[2][4] = {};
#pragma unroll
    for (int ks = 0; ks < 2; ++ks)
#pragma unroll
      for (int g = 0; g < 4; ++g) {
        bf16x8 kf = *reinterpret_cast<const bf16x8*>(
            Kb + (g * 16 + lm) * 128 + ((lw * 16 + ks * 64) ^ (l7 << 4)));
        st[0][g] = __builtin_amdgcn_mfma_f32_16x16x32_bf16(kf, qf[0][ks], st[0][g], 0, 0, 0);
        st[1][g] = __builtin_amdgcn_mfma_f32_16x16x32_bf16(kf, qf[1][ks], st[1][g], 0, 0, 0);
      }

    // p = 2^s (bounded, no max); accumulate row-sum partials; write P bf16
#pragma unroll
    for (int qm = 0; qm < 2; ++qm)
#pragma unroll
      for (int g = 0; g < 4; ++g) {
        f32x4 s4 = st[qm][g];
        float p0 = __builtin_amdgcn_exp2f(s4.x);
        float p1 = __builtin_amdgcn_exp2f(s4.y);
        float p2 = __builtin_amdgcn_exp2f(s4.z);
        float p3 = __builtin_amdgcn_exp2f(s4.w);
        l_acc[qm] += (p0 + p1) + (p2 + p3);
        uint off = (uint)((qm * 16 + lm) * 128 + ((g * 32 + lw * 8) ^ (l7 << 4)));
        *reinterpret_cast<uint*>(Pbase + off)     = pack_bf16(p0, p1);
        *reinterpret_cast<uint*>(Pbase + off + 4) = pack_bf16(p2, p3);
      }

    // P fragments (B-operand): lane holds P[q0+lm][8*lw+i+32*ks]
    bf16x8 pf[2][2];
#pragma unroll
    for (int qm = 0; qm < 2; ++qm)
#pragma unroll
      for (int ks = 0; ks < 2; ++ks)
        pf[qm][ks] = *reinterpret_cast<const bf16x8*>(
            Pbase + (qm * 16 + lm) * 128 + ((lw * 16 + ks * 64) ^ (l7 << 4)));

    // O^T += V^T * P^T
#pragma unroll
    for (int ks = 0; ks < 2; ++ks)
#pragma unroll
      for (int dn = 0; dn < 4; ++dn) {
        bf16x8 vf = *reinterpret_cast<const bf16x8*>(
            Vb + (dn * 16 + lm) * 128 + ((lw * 16 + ks * 64) ^ (l7 << 4)));
        oacc[0][dn] = __builtin_amdgcn_mfma_f32_16x16x32_bf16(vf, pf[0][ks], oacc[0][dn], 0, 0, 0);
        oacc[1][dn] = __builtin_amdgcn_mfma_f32_16x16x32_bf16(vf, pf[1][ks], oacc[1][dn], 0, 0, 0);
      }
    __syncthreads();
  }

  // epilogue: finish row sums (4 lanes share a q-row), normalize, store fp32
#pragma unroll
  for (int qm = 0; qm < 2; ++qm) {
    float ls = l_acc[qm];
    ls += __shfl_xor(ls, 16);
    ls += __shfl_xor(ls, 32);
    float inv = 1.f / ls;
    const int qg = qb * 128 + w4 * 32 + qm * 16 + lm;
#pragma unroll
    for (int dn = 0; dn < 4; ++dn) {
      f32x4 o = oacc[qm][dn];
      o *= inv;
      *reinterpret_cast<f32x4*>(
          &outp[((size_t)b * SEQ + qg) * DIM + h * HD + dn * 16 + lw * 4]) = o;
    }
  }
}

// ---------------- launch -----------------------------------------------------
extern "C" void kernel_launch(void* const* d_in, const int* in_sizes, int n_in,
                              void* d_out, int out_size, void* d_ws, size_t ws_size,
                              hipStream_t stream) {
  const float* x       = (const float*)d_in[0];
  const float* Wqkv    = (const float*)d_in[1];
  const float* Wout    = (const float*)d_in[2];
  const float* q_scale = (const float*)d_in[3];
  const float* k_scale = (const float*)d_in[4];
  float* out = (float*)d_out;

  char* ws = (char*)d_ws;
  float* qkv = (float*)ws;                                     // 4096*3072 f32 (50.3MB)
  size_t off = (size_t)MROW * N3 * 4;
  ushort_t* qT = (ushort_t*)(ws + off); off += (size_t)NB * NH * SEQ * HD * 2;
  ushort_t* kT = (ushort_t*)(ws + off); off += (size_t)NB * NH * SEQ * HD * 2;
  ushort_t* vT = (ushort_t*)(ws + off); off += (size_t)NB * NH * SEQ * HD * 2;
  float* tab = (float*)(ws + off);
  float* attn_out = qkv;                                       // reuse qkv region

  rope_table_kernel<<<dim3(SEQ * 32 / 256), dim3(256), 0, stream>>>(tab);
  gemm_nt_kernel<<<dim3(N3 / 128, MROW / 128), dim3(256), 0, stream>>>(x, Wqkv, qkv, N3, DIM);
  qkv_post_kernel<<<dim3(NB * 32 * NH), dim3(256), 0, stream>>>(qkv, q_scale, k_scale, tab, qT, kT, vT);
  attn_mfma_kernel<<<dim3(16, NB * NH), dim3(256), 0, stream>>>(qT, kT, vT, attn_out);
  gemm_nt_kernel<<<dim3(DIM / 128, MROW / 128), dim3(256), 0, stream>>>(attn_out, Wout, out, DIM, DIM);
}

// Round 4
// 160.816 us; speedup vs baseline: 8.5252x; 3.0193x over previous
//
#include <hip/hip_runtime.h>
#include <hip/hip_bf16.h>
#include <cstddef>

typedef unsigned int uint;
typedef unsigned short ushort_t;
typedef __attribute__((ext_vector_type(8))) short bf16x8;
typedef __attribute__((ext_vector_type(4))) float f32x4;

constexpr int NB   = 2;
constexpr int NP   = 256;
constexpr int DIM  = 1024;
constexpr int NH   = 16;
constexpr int HD   = 64;
constexpr int SEQ  = 2048;
constexpr int MROW = NB * SEQ;      // 4096
constexpr int N3   = 3 * DIM;       // 3072
// softmax in base-2: fold hd^-0.5 * log2(e) into q
constexpr float QS = 0.125f * 1.4426950408889634f;

__device__ __forceinline__ ushort_t f2bf(float x) {
  uint u = __builtin_bit_cast(uint, x);
  u = (u + 0x7fff + ((u >> 16) & 1)) >> 16;   // round-to-nearest-even
  return (ushort_t)u;
}
__device__ __forceinline__ uint pack_bf16(float a, float b) {
  return (uint)f2bf(a) | ((uint)f2bf(b) << 16);
}
__device__ __forceinline__ float bf2f(ushort_t h) {
  return __builtin_bit_cast(float, (uint)h << 16);
}

__device__ __forceinline__ void gload16(const void* g, void* l) {
  __builtin_amdgcn_global_load_lds((const __attribute__((address_space(1))) uint*)g,
                                   (__attribute__((address_space(3))) uint*)l, 16, 0, 0);
}

// ---------------- K0: RoPE cos/sin table ------------------------------------
__global__ __launch_bounds__(256) void rope_table_kernel(float* __restrict__ tab) {
  int idx = blockIdx.x * 256 + threadIdx.x;
  if (idx >= SEQ * 32) return;
  int l = idx >> 5, i = idx & 31;
  float j = (float)(i & 15);
  float invf = exp2f(-j * (13.287712379549449f / 16.f));
  float pos = (i < 16) ? (float)(l >> 8) : (float)(l & (NP - 1));
  float ang = pos * invf;
  tab[idx]            = cosf(ang);
  tab[SEQ * 32 + idx] = sinf(ang);
}

// ---------------- conversions ------------------------------------------------
__global__ __launch_bounds__(256) void cvt_bf16_kernel(
    const float* __restrict__ s, ushort_t* __restrict__ d, int n4) {
  int i = blockIdx.x * 256 + threadIdx.x;
  if (i >= n4) return;
  float4 v = reinterpret_cast<const float4*>(s)[i];
  uint2 o; o.x = pack_bf16(v.x, v.y); o.y = pack_bf16(v.z, v.w);
  reinterpret_cast<uint2*>(d)[i] = o;
}

__global__ __launch_bounds__(256) void cvt_split_kernel(
    const float* __restrict__ s, ushort_t* __restrict__ hi,
    ushort_t* __restrict__ lo, int n4) {
  int i = blockIdx.x * 256 + threadIdx.x;
  if (i >= n4) return;
  float4 v = reinterpret_cast<const float4*>(s)[i];
  float f[4] = {v.x, v.y, v.z, v.w};
  ushort_t h[4], l[4];
#pragma unroll
  for (int j = 0; j < 4; ++j) {
    h[j] = f2bf(f[j]);
    l[j] = f2bf(f[j] - bf2f(h[j]));
  }
  uint2 oh{(uint)h[0] | ((uint)h[1] << 16), (uint)h[2] | ((uint)h[3] << 16)};
  uint2 ol{(uint)l[0] | ((uint)l[1] << 16), (uint)l[2] | ((uint)l[3] << 16)};
  reinterpret_cast<uint2*>(hi)[i] = oh;
  reinterpret_cast<uint2*>(lo)[i] = ol;
}

// ---------------- bf16 MFMA GEMM: C[M][N] = A[M][K] * B[N][K]^T --------------
// BN=128, BK=64, 4 waves (2x2), per-wave (BM/2)x64 output, 16x16x32 MFMA.
// LDS swizzle: chunk c at row r holds global chunk c^(r&7); staged via
// pre-swizzled global source (linear LDS dest), read with same XOR.
// SPLIT: C = Ah*Bh + Al*Bh + Ah*Bl (near-fp32 precision at MFMA rate).
template<int BM, bool SPLIT>
__global__ __launch_bounds__(256) void gemm_mfma_kernel(
    const ushort_t* __restrict__ Ah_, const ushort_t* __restrict__ Al_,
    const ushort_t* __restrict__ Bh_, const ushort_t* __restrict__ Bl_,
    float* __restrict__ C, int N, int K) {
  constexpr int MF = BM / 32;               // m-frags per wave
  constexpr int REG = (BM + 128) * 128;     // bytes per (A,B) tile pair
  __shared__ __align__(16) char smem[(SPLIT ? 2 : 1) * REG];
  const int tid = threadIdx.x;
  const int l = tid & 63, w4 = tid >> 6;
  const int l7 = l & 7, l3 = l >> 3, lm = l & 15, lw = l >> 4;
  const int wm = w4 >> 1, wn = w4 & 1;
  const int bm = blockIdx.y * BM, bn = blockIdx.x * 128;
  const uint rloc = (uint)(w4 * 8 + l3);
  const uint csrc = (uint)((l7 ^ l3) << 4);
  const uint sw = (uint)(lm & 7);

  f32x4 acc[MF][4] = {};

  auto stageAB = [&](const ushort_t* A_, const ushort_t* B_, int dstoff, int k0) {
    const char* Ab = reinterpret_cast<const char*>(A_);
    const char* Bb = reinterpret_cast<const char*>(B_);
#pragma unroll
    for (int i = 0; i < BM / 32; ++i)
      gload16(Ab + (((size_t)(bm + i * 32 + rloc) * K + k0) << 1) + csrc,
              smem + dstoff + (i * 32 + w4 * 8) * 128);
#pragma unroll
    for (int i = 0; i < 4; ++i)
      gload16(Bb + (((size_t)(bn + i * 32 + rloc) * K + k0) << 1) + csrc,
              smem + dstoff + BM * 128 + (i * 32 + w4 * 8) * 128);
  };

  for (int k0 = 0; k0 < K; k0 += 64) {
    stageAB(Ah_, Bh_, 0, k0);
    if constexpr (SPLIT) stageAB(Al_, Bl_, REG, k0);
    __syncthreads();
    const char* As = smem;
    const char* Bs = smem + BM * 128;
    bf16x8 af[MF][2], bfr[4][2];
#pragma unroll
    for (int mi = 0; mi < MF; ++mi)
#pragma unroll
      for (int ks = 0; ks < 2; ++ks)
        af[mi][ks] = *reinterpret_cast<const bf16x8*>(
            As + (wm * (BM / 2) + mi * 16 + lm) * 128 + ((((uint)ks * 4 + lw) ^ sw) << 4));
#pragma unroll
    for (int ni = 0; ni < 4; ++ni)
#pragma unroll
      for (int ks = 0; ks < 2; ++ks)
        bfr[ni][ks] = *reinterpret_cast<const bf16x8*>(
            Bs + (wn * 64 + ni * 16 + lm) * 128 + ((((uint)ks * 4 + lw) ^ sw) << 4));
#pragma unroll
    for (int ks = 0; ks < 2; ++ks)
#pragma unroll
      for (int mi = 0; mi < MF; ++mi)
#pragma unroll
        for (int ni = 0; ni < 4; ++ni)
          acc[mi][ni] = __builtin_amdgcn_mfma_f32_16x16x32_bf16(
              af[mi][ks], bfr[ni][ks], acc[mi][ni], 0, 0, 0);
    if constexpr (SPLIT) {
      const char* As2 = smem + REG;
      const char* Bs2 = smem + REG + BM * 128;
      bf16x8 al[MF][2], bl[4][2];
#pragma unroll
      for (int mi = 0; mi < MF; ++mi)
#pragma unroll
        for (int ks = 0; ks < 2; ++ks)
          al[mi][ks] = *reinterpret_cast<const bf16x8*>(
              As2 + (wm * (BM / 2) + mi * 16 + lm) * 128 + ((((uint)ks * 4 + lw) ^ sw) << 4));
#pragma unroll
      for (int ni = 0; ni < 4; ++ni)
#pragma unroll
        for (int ks = 0; ks < 2; ++ks)
          bl[ni][ks] = *reinterpret_cast<const bf16x8*>(
              Bs2 + (wn * 64 + ni * 16 + lm) * 128 + ((((uint)ks * 4 + lw) ^ sw) << 4));
#pragma unroll
      for (int ks = 0; ks < 2; ++ks)
#pragma unroll
        for (int mi = 0; mi < MF; ++mi)
#pragma unroll
          for (int ni = 0; ni < 4; ++ni) {
            acc[mi][ni] = __builtin_amdgcn_mfma_f32_16x16x32_bf16(
                al[mi][ks], bfr[ni][ks], acc[mi][ni], 0, 0, 0);
            acc[mi][ni] = __builtin_amdgcn_mfma_f32_16x16x32_bf16(
                af[mi][ks], bl[ni][ks], acc[mi][ni], 0, 0, 0);
          }
    }
    __syncthreads();
  }
#pragma unroll
  for (int mi = 0; mi < MF; ++mi)
#pragma unroll
    for (int ni = 0; ni < 4; ++ni) {
      f32x4 a = acc[mi][ni];
      const int row0 = bm + wm * (BM / 2) + mi * 16 + lw * 4;
      const int col  = bn + wn * 64 + ni * 16 + lm;
#pragma unroll
      for (int r = 0; r < 4; ++r)
        C[(size_t)(row0 + r) * N + col] = a[r];
    }
}

// ---------------- K2: RMSNorm + RoPE + bf16 cast; qT/kT row-major, vT d-major
__global__ __launch_bounds__(256) void qkv_post_kernel(
    const float* __restrict__ qkv, const float* __restrict__ qs,
    const float* __restrict__ ksc, const float* __restrict__ tab,
    ushort_t* __restrict__ qT, ushort_t* __restrict__ kT, ushort_t* __restrict__ vT) {
  __shared__ ushort_t vt[64][72];
  const int bx = blockIdx.x;
  const int h = bx & 15, lt = (bx >> 4) & 31, b = bx >> 9;
  const int t = threadIdx.x, lr = t >> 2, s = t & 3, d0 = s * 16;
  const int lg = lt * 64 + lr;
  const int bh = b * NH + h;
  const float* rowp = qkv + ((size_t)(b * SEQ + lg) * N3) + h * HD + d0;

  float4 q4[4], k4[4], v4[4], qs4[4], ks4[4];
#pragma unroll
  for (int u = 0; u < 4; ++u) {
    q4[u]  = *reinterpret_cast<const float4*>(rowp + u * 4);
    k4[u]  = *reinterpret_cast<const float4*>(rowp + DIM + u * 4);
    v4[u]  = *reinterpret_cast<const float4*>(rowp + 2 * DIM + u * 4);
    qs4[u] = *reinterpret_cast<const float4*>(qs + d0 + u * 4);
    ks4[u] = *reinterpret_cast<const float4*>(ksc + d0 + u * 4);
  }
  const float* vq = reinterpret_cast<const float*>(q4);
  const float* vk = reinterpret_cast<const float*>(k4);
  const float* vv = reinterpret_cast<const float*>(v4);
  const float* sq_ = reinterpret_cast<const float*>(qs4);
  const float* sk_ = reinterpret_cast<const float*>(ks4);

  float sq = 0.f, sk = 0.f;
#pragma unroll
  for (int j = 0; j < 16; ++j) { sq = fmaf(vq[j], vq[j], sq); sk = fmaf(vk[j], vk[j], sk); }
  sq += __shfl_xor(sq, 1); sq += __shfl_xor(sq, 2);
  sk += __shfl_xor(sk, 1); sk += __shfl_xor(sk, 2);
  float rq = rsqrtf(sq * (1.f / HD) + 1e-6f);
  float rk = rsqrtf(sk * (1.f / HD) + 1e-6f);

  float4 c4[2], s4[2];
  const float* tc = tab + (size_t)lg * 32 + s * 8;
  const float* ts = tab + (size_t)SEQ * 32 + (size_t)lg * 32 + s * 8;
  c4[0] = *reinterpret_cast<const float4*>(tc);
  c4[1] = *reinterpret_cast<const float4*>(tc + 4);
  s4[0] = *reinterpret_cast<const float4*>(ts);
  s4[1] = *reinterpret_cast<const float4*>(ts + 4);
  const float* cj = reinterpret_cast<const float*>(c4);
  const float* sj = reinterpret_cast<const float*>(s4);

  uint uq[8], uk[8], uv[8];
#pragma unroll
  for (int j = 0; j < 8; ++j) {
    float qe = vq[2*j] * rq * sq_[2*j], qo = vq[2*j+1] * rq * sq_[2*j+1];
    float ke = vk[2*j] * rk * sk_[2*j], ko = vk[2*j+1] * rk * sk_[2*j+1];
    float c = cj[j], sn = sj[j];
    uq[j] = pack_bf16((qe * c - qo * sn) * QS, (qe * sn + qo * c) * QS);
    uk[j] = pack_bf16(ke * c - ko * sn, ke * sn + ko * c);
    uv[j] = pack_bf16(vv[2*j], vv[2*j+1]);
  }
  ushort_t* qp = qT + ((size_t)bh * SEQ + lg) * HD + d0;
  ushort_t* kp = kT + ((size_t)bh * SEQ + lg) * HD + d0;
  reinterpret_cast<uint4*>(qp)[0] = *reinterpret_cast<uint4*>(&uq[0]);
  reinterpret_cast<uint4*>(qp)[1] = *reinterpret_cast<uint4*>(&uq[4]);
  reinterpret_cast<uint4*>(kp)[0] = *reinterpret_cast<uint4*>(&uk[0]);
  reinterpret_cast<uint4*>(kp)[1] = *reinterpret_cast<uint4*>(&uk[4]);
#pragma unroll
  for (int j = 0; j < 16; ++j)
    vt[d0 + j][lr] = (ushort_t)((j & 1) ? (uv[j >> 1] >> 16) : (uv[j >> 1] & 0xffff));
  __syncthreads();
  const int drow = t >> 2, lc = (t & 3) * 16;
  ushort_t* vp = vT + ((size_t)bh * HD + drow) * SEQ + lt * 64 + lc;
  reinterpret_cast<uint4*>(vp)[0] = *reinterpret_cast<const uint4*>(&vt[drow][lc]);
  reinterpret_cast<uint4*>(vp)[1] = *reinterpret_cast<const uint4*>(&vt[drow][lc + 8]);
}

// ---------------- K3: bf16 MFMA block-causal flash attention -----------------
// Emits hi/lo split-bf16 output for the split out-projection GEMM.
__global__ __launch_bounds__(256) void attn_mfma_kernel(
    const ushort_t* __restrict__ qT, const ushort_t* __restrict__ kT,
    const ushort_t* __restrict__ vT, ushort_t* __restrict__ ahi,
    ushort_t* __restrict__ alo) {
  __shared__ __align__(16) char smem[49152];
  const int tid = threadIdx.x;
  const int l  = tid & 63, w4 = tid >> 6;
  const int lm = l & 15, lw = l >> 4, l7 = l & 7, l3 = l >> 3;
  const int bh = blockIdx.y, b = bh >> 4, h = bh & 15;
  const int qb = (int)gridDim.x - 1 - (int)blockIdx.x;
  const int nkb = ((qb >> 1) + 1) * 4;

  bf16x8 qf[2][2];
  const size_t qrow0 = (size_t)bh * SEQ + qb * 128 + w4 * 32;
#pragma unroll
  for (int qm = 0; qm < 2; ++qm)
#pragma unroll
    for (int ks = 0; ks < 2; ++ks)
      qf[qm][ks] = *reinterpret_cast<const bf16x8*>(
          qT + (qrow0 + qm * 16 + lm) * HD + lw * 8 + ks * 32);

  const char* kTb = reinterpret_cast<const char*>(kT + (size_t)bh * SEQ * HD);
  const char* vTb = reinterpret_cast<const char*>(vT + (size_t)bh * HD * SEQ);
  const uint rloc = w4 * 8 + l3;
  const uint csrc = (uint)((l7 ^ l3) << 4);
  char* Pbase = smem + 32768 + w4 * 4096;

  float l_acc[2] = {0.f, 0.f};
  f32x4 oacc[2][4] = {};

  auto stage = [&](int kb, int buf) {
    const char* sK = kTb + ((size_t)(kb * 64) + rloc) * 128 + csrc;
    const char* sV = vTb + (size_t)rloc * (SEQ * 2) + (size_t)kb * 128 + csrc;
    char* dK = smem + buf * 16384 + w4 * 1024;
    char* dV = dK + 8192;
    gload16(sK, dK);
    gload16(sK + 4096, dK + 4096);
    gload16(sV, dV);
    gload16(sV + (size_t)32 * SEQ * 2, dV + 4096);
  };

  stage(0, 0);
  __syncthreads();

  for (int kb = 0; kb < nkb; ++kb) {
    const int buf = kb & 1;
    if (kb + 1 < nkb) stage(kb + 1, buf ^ 1);
    const char* Kb = smem + buf * 16384;
    const char* Vb = Kb + 8192;

    f32x4 st[2][4] = {};
#pragma unroll
    for (int ks = 0; ks < 2; ++ks)
#pragma unroll
      for (int g = 0; g < 4; ++g) {
        bf16x8 kf = *reinterpret_cast<const bf16x8*>(
            Kb + (g * 16 + lm) * 128 + ((lw * 16 + ks * 64) ^ (l7 << 4)));
        st[0][g] = __builtin_amdgcn_mfma_f32_16x16x32_bf16(kf, qf[0][ks], st[0][g], 0, 0, 0);
        st[1][g] = __builtin_amdgcn_mfma_f32_16x16x32_bf16(kf, qf[1][ks], st[1][g], 0, 0, 0);
      }

#pragma unroll
    for (int qm = 0; qm < 2; ++qm)
#pragma unroll
      for (int g = 0; g < 4; ++g) {
        f32x4 s4 = st[qm][g];
        float p0 = __builtin_amdgcn_exp2f(s4.x);
        float p1 = __builtin_amdgcn_exp2f(s4.y);
        float p2 = __builtin_amdgcn_exp2f(s4.z);
        float p3 = __builtin_amdgcn_exp2f(s4.w);
        l_acc[qm] += (p0 + p1) + (p2 + p3);
        uint off = (uint)((qm * 16 + lm) * 128 + ((g * 32 + lw * 8) ^ (l7 << 4)));
        *reinterpret_cast<uint*>(Pbase + off)     = pack_bf16(p0, p1);
        *reinterpret_cast<uint*>(Pbase + off + 4) = pack_bf16(p2, p3);
      }

    bf16x8 pf[2][2];
#pragma unroll
    for (int qm = 0; qm < 2; ++qm)
#pragma unroll
      for (int ks = 0; ks < 2; ++ks)
        pf[qm][ks] = *reinterpret_cast<const bf16x8*>(
            Pbase + (qm * 16 + lm) * 128 + ((lw * 16 + ks * 64) ^ (l7 << 4)));

#pragma unroll
    for (int ks = 0; ks < 2; ++ks)
#pragma unroll
      for (int dn = 0; dn < 4; ++dn) {
        bf16x8 vf = *reinterpret_cast<const bf16x8*>(
            Vb + (dn * 16 + lm) * 128 + ((lw * 16 + ks * 64) ^ (l7 << 4)));
        oacc[0][dn] = __builtin_amdgcn_mfma_f32_16x16x32_bf16(vf, pf[0][ks], oacc[0][dn], 0, 0, 0);
        oacc[1][dn] = __builtin_amdgcn_mfma_f32_16x16x32_bf16(vf, pf[1][ks], oacc[1][dn], 0, 0, 0);
      }
    __syncthreads();
  }

#pragma unroll
  for (int qm = 0; qm < 2; ++qm) {
    float ls = l_acc[qm];
    ls += __shfl_xor(ls, 16);
    ls += __shfl_xor(ls, 32);
    float inv = 1.f / ls;
    const int qg = qb * 128 + w4 * 32 + qm * 16 + lm;
#pragma unroll
    for (int dn = 0; dn < 4; ++dn) {
      f32x4 o = oacc[qm][dn];
      o *= inv;
      ushort_t hh[4], ll[4];
#pragma unroll
      for (int j = 0; j < 4; ++j) {
        hh[j] = f2bf(o[j]);
        ll[j] = f2bf(o[j] - bf2f(hh[j]));
      }
      size_t off = ((size_t)b * SEQ + qg) * DIM + h * HD + dn * 16 + lw * 4;
      uint2 uh{(uint)hh[0] | ((uint)hh[1] << 16), (uint)hh[2] | ((uint)hh[3] << 16)};
      uint2 ul{(uint)ll[0] | ((uint)ll[1] << 16), (uint)ll[2] | ((uint)ll[3] << 16)};
      *reinterpret_cast<uint2*>(&ahi[off]) = uh;
      *reinterpret_cast<uint2*>(&alo[off]) = ul;
    }
  }
}

// ---------------- launch -----------------------------------------------------
extern "C" void kernel_launch(void* const* d_in, const int* in_sizes, int n_in,
                              void* d_out, int out_size, void* d_ws, size_t ws_size,
                              hipStream_t stream) {
  const float* x       = (const float*)d_in[0];
  const float* Wqkv    = (const float*)d_in[1];
  const float* Wout    = (const float*)d_in[2];
  const float* q_scale = (const float*)d_in[3];
  const float* k_scale = (const float*)d_in[4];
  float* out = (float*)d_out;

  char* ws = (char*)d_ws;
  float* qkv = (float*)ws;                                 // 50.33 MB fp32
  ushort_t* attn_hi = (ushort_t*)ws;                       // reuse qkv region
  ushort_t* attn_lo = attn_hi + (size_t)MROW * DIM;
  size_t off = (size_t)MROW * N3 * 4;
  ushort_t* qT = (ushort_t*)(ws + off); off += (size_t)NB * NH * SEQ * HD * 2;
  ushort_t* kT = (ushort_t*)(ws + off); off += (size_t)NB * NH * SEQ * HD * 2;
  ushort_t* vT = (ushort_t*)(ws + off); off += (size_t)NB * NH * SEQ * HD * 2;
  float* tab   = (float*)(ws + off);    off += (size_t)SEQ * 64 * 4;
  ushort_t* xh  = (ushort_t*)(ws + off); off += (size_t)MROW * DIM * 2;
  ushort_t* wqh = (ushort_t*)(ws + off); off += (size_t)N3 * DIM * 2;
  ushort_t* woh = (ushort_t*)(ws + off); off += (size_t)DIM * DIM * 2;
  ushort_t* wol = (ushort_t*)(ws + off);

  rope_table_kernel<<<dim3(SEQ * 32 / 256), dim3(256), 0, stream>>>(tab);
  cvt_bf16_kernel<<<dim3(MROW * DIM / 4 / 256), dim3(256), 0, stream>>>(x, xh, MROW * DIM / 4);
  cvt_bf16_kernel<<<dim3(N3 * DIM / 4 / 256), dim3(256), 0, stream>>>(Wqkv, wqh, N3 * DIM / 4);
  cvt_split_kernel<<<dim3(DIM * DIM / 4 / 256), dim3(256), 0, stream>>>(Wout, woh, wol, DIM * DIM / 4);
  gemm_mfma_kernel<128, false><<<dim3(N3 / 128, MROW / 128), dim3(256), 0, stream>>>(
      xh, nullptr, wqh, nullptr, qkv, N3, DIM);
  qkv_post_kernel<<<dim3(NB * 32 * NH), dim3(256), 0, stream>>>(qkv, q_scale, k_scale, tab, qT, kT, vT);
  attn_mfma_kernel<<<dim3(16, NB * NH), dim3(256), 0, stream>>>(qT, kT, vT, attn_hi, attn_lo);
  gemm_mfma_kernel<64, true><<<dim3(DIM / 128, MROW / 64), dim3(256), 0, stream>>>(
      attn_hi, attn_lo, woh, wol, out, DIM, DIM);
}

// Round 5
// 148.157 us; speedup vs baseline: 9.2537x; 1.0854x over previous
//
#include <hip/hip_runtime.h>
#include <hip/hip_bf16.h>
#include <cstddef>

typedef unsigned int uint;
typedef unsigned short ushort_t;
typedef __attribute__((ext_vector_type(8))) short bf16x8;
typedef __attribute__((ext_vector_type(4))) float f32x4;

constexpr int NB   = 2;
constexpr int NP   = 256;
constexpr int DIM  = 1024;
constexpr int NH   = 16;
constexpr int HD   = 64;
constexpr int SEQ  = 2048;
constexpr int MROW = NB * SEQ;      // 4096
constexpr int N3   = 3 * DIM;       // 3072
// softmax in base-2: fold hd^-0.5 * log2(e) into q
constexpr float QS = 0.125f * 1.4426950408889634f;

__device__ __forceinline__ ushort_t f2bf(float x) {
  uint u = __builtin_bit_cast(uint, x);
  u = (u + 0x7fff + ((u >> 16) & 1)) >> 16;   // round-to-nearest-even
  return (ushort_t)u;
}
__device__ __forceinline__ uint pack_bf16(float a, float b) {
  __hip_bfloat162 h = __float22bfloat162_rn(float2{a, b});
  uint u; __builtin_memcpy(&u, &h, 4);        // v_cvt_pk_bf16_f32
  return u;
}
__device__ __forceinline__ float bf2f(ushort_t h) {
  return __builtin_bit_cast(float, (uint)h << 16);
}

__device__ __forceinline__ void gload16(const void* g, void* l) {
  __builtin_amdgcn_global_load_lds((const __attribute__((address_space(1))) uint*)g,
                                   (__attribute__((address_space(3))) uint*)l, 16, 0, 0);
}

// ---------------- K0: RoPE cos/sin table ------------------------------------
__global__ __launch_bounds__(256) void rope_table_kernel(float* __restrict__ tab) {
  int idx = blockIdx.x * 256 + threadIdx.x;
  if (idx >= SEQ * 32) return;
  int l = idx >> 5, i = idx & 31;
  float j = (float)(i & 15);
  float invf = exp2f(-j * (13.287712379549449f / 16.f));
  float pos = (i < 16) ? (float)(l >> 8) : (float)(l & (NP - 1));
  float ang = pos * invf;
  tab[idx]            = cosf(ang);
  tab[SEQ * 32 + idx] = sinf(ang);
}

// ---------------- conversions ------------------------------------------------
__global__ __launch_bounds__(256) void cvt_bf16_kernel(
    const float* __restrict__ s, ushort_t* __restrict__ d, int n4) {
  int i = blockIdx.x * 256 + threadIdx.x;
  if (i >= n4) return;
  float4 v = reinterpret_cast<const float4*>(s)[i];
  uint2 o; o.x = pack_bf16(v.x, v.y); o.y = pack_bf16(v.z, v.w);
  reinterpret_cast<uint2*>(d)[i] = o;
}

__global__ __launch_bounds__(256) void cvt_split_kernel(
    const float* __restrict__ s, ushort_t* __restrict__ hi,
    ushort_t* __restrict__ lo, int n4) {
  int i = blockIdx.x * 256 + threadIdx.x;
  if (i >= n4) return;
  float4 v = reinterpret_cast<const float4*>(s)[i];
  float f[4] = {v.x, v.y, v.z, v.w};
  ushort_t h[4], l[4];
#pragma unroll
  for (int j = 0; j < 4; ++j) {
    h[j] = f2bf(f[j]);
    l[j] = f2bf(f[j] - bf2f(h[j]));
  }
  uint2 oh{(uint)h[0] | ((uint)h[1] << 16), (uint)h[2] | ((uint)h[3] << 16)};
  uint2 ol{(uint)l[0] | ((uint)l[1] << 16), (uint)l[2] | ((uint)l[3] << 16)};
  reinterpret_cast<uint2*>(hi)[i] = oh;
  reinterpret_cast<uint2*>(lo)[i] = ol;
}

// ---------------- bf16 MFMA GEMM: C[M][N] = A[M][K] * B[N][K]^T --------------
template<int BM, bool SPLIT, bool BF16OUT>
__global__ __launch_bounds__(256) void gemm_mfma_kernel(
    const ushort_t* __restrict__ Ah_, const ushort_t* __restrict__ Al_,
    const ushort_t* __restrict__ Bh_, const ushort_t* __restrict__ Bl_,
    void* __restrict__ Cv, int N, int K) {
  constexpr int MF = BM / 32;               // m-frags per wave
  constexpr int REG = (BM + 128) * 128;     // bytes per (A,B) tile pair
  __shared__ __align__(16) char smem[(SPLIT ? 2 : 1) * REG];
  const int tid = threadIdx.x;
  const int l = tid & 63, w4 = tid >> 6;
  const int l7 = l & 7, l3 = l >> 3, lm = l & 15, lw = l >> 4;
  const int wm = w4 >> 1, wn = w4 & 1;
  const int bm = blockIdx.y * BM, bn = blockIdx.x * 128;
  const uint rloc = (uint)(w4 * 8 + l3);
  const uint csrc = (uint)((l7 ^ l3) << 4);
  const uint sw = (uint)(lm & 7);

  f32x4 acc[MF][4] = {};

  auto stageAB = [&](const ushort_t* A_, const ushort_t* B_, int dstoff, int k0) {
    const char* Ab = reinterpret_cast<const char*>(A_);
    const char* Bb = reinterpret_cast<const char*>(B_);
#pragma unroll
    for (int i = 0; i < BM / 32; ++i)
      gload16(Ab + (((size_t)(bm + i * 32 + rloc) * K + k0) << 1) + csrc,
              smem + dstoff + (i * 32 + w4 * 8) * 128);
#pragma unroll
    for (int i = 0; i < 4; ++i)
      gload16(Bb + (((size_t)(bn + i * 32 + rloc) * K + k0) << 1) + csrc,
              smem + dstoff + BM * 128 + (i * 32 + w4 * 8) * 128);
  };

  for (int k0 = 0; k0 < K; k0 += 64) {
    stageAB(Ah_, Bh_, 0, k0);
    if constexpr (SPLIT) stageAB(Al_, Bl_, REG, k0);
    __syncthreads();
    const char* As = smem;
    const char* Bs = smem + BM * 128;
    bf16x8 af[MF][2], bfr[4][2];
#pragma unroll
    for (int mi = 0; mi < MF; ++mi)
#pragma unroll
      for (int ks = 0; ks < 2; ++ks)
        af[mi][ks] = *reinterpret_cast<const bf16x8*>(
            As + (wm * (BM / 2) + mi * 16 + lm) * 128 + ((((uint)ks * 4 + lw) ^ sw) << 4));
#pragma unroll
    for (int ni = 0; ni < 4; ++ni)
#pragma unroll
      for (int ks = 0; ks < 2; ++ks)
        bfr[ni][ks] = *reinterpret_cast<const bf16x8*>(
            Bs + (wn * 64 + ni * 16 + lm) * 128 + ((((uint)ks * 4 + lw) ^ sw) << 4));
#pragma unroll
    for (int ks = 0; ks < 2; ++ks)
#pragma unroll
      for (int mi = 0; mi < MF; ++mi)
#pragma unroll
        for (int ni = 0; ni < 4; ++ni)
          acc[mi][ni] = __builtin_amdgcn_mfma_f32_16x16x32_bf16(
              af[mi][ks], bfr[ni][ks], acc[mi][ni], 0, 0, 0);
    if constexpr (SPLIT) {
      const char* As2 = smem + REG;
      const char* Bs2 = smem + REG + BM * 128;
      bf16x8 al[MF][2], bl[4][2];
#pragma unroll
      for (int mi = 0; mi < MF; ++mi)
#pragma unroll
        for (int ks = 0; ks < 2; ++ks)
          al[mi][ks] = *reinterpret_cast<const bf16x8*>(
              As2 + (wm * (BM / 2) + mi * 16 + lm) * 128 + ((((uint)ks * 4 + lw) ^ sw) << 4));
#pragma unroll
      for (int ni = 0; ni < 4; ++ni)
#pragma unroll
        for (int ks = 0; ks < 2; ++ks)
          bl[ni][ks] = *reinterpret_cast<const bf16x8*>(
              Bs2 + (wn * 64 + ni * 16 + lm) * 128 + ((((uint)ks * 4 + lw) ^ sw) << 4));
#pragma unroll
      for (int ks = 0; ks < 2; ++ks)
#pragma unroll
        for (int mi = 0; mi < MF; ++mi)
#pragma unroll
          for (int ni = 0; ni < 4; ++ni) {
            acc[mi][ni] = __builtin_amdgcn_mfma_f32_16x16x32_bf16(
                al[mi][ks], bfr[ni][ks], acc[mi][ni], 0, 0, 0);
            acc[mi][ni] = __builtin_amdgcn_mfma_f32_16x16x32_bf16(
                af[mi][ks], bl[ni][ks], acc[mi][ni], 0, 0, 0);
          }
    }
    __syncthreads();
  }
#pragma unroll
  for (int mi = 0; mi < MF; ++mi)
#pragma unroll
    for (int ni = 0; ni < 4; ++ni) {
      f32x4 a = acc[mi][ni];
      const int row0 = bm + wm * (BM / 2) + mi * 16 + lw * 4;
      const int col  = bn + wn * 64 + ni * 16 + lm;
      if constexpr (BF16OUT) {
        ushort_t* Cb = (ushort_t*)Cv;
#pragma unroll
        for (int r = 0; r < 4; ++r)
          Cb[(size_t)(row0 + r) * N + col] = f2bf(a[r]);
      } else {
        float* Cf = (float*)Cv;
#pragma unroll
        for (int r = 0; r < 4; ++r)
          Cf[(size_t)(row0 + r) * N + col] = a[r];
      }
    }
}

// ---------------- K2: RMSNorm + RoPE (bf16 in); qT/kT row-major, vT d-major --
__global__ __launch_bounds__(256) void qkv_post_kernel(
    const ushort_t* __restrict__ qkv, const float* __restrict__ qs,
    const float* __restrict__ ksc, const float* __restrict__ tab,
    ushort_t* __restrict__ qT, ushort_t* __restrict__ kT, ushort_t* __restrict__ vT) {
  __shared__ ushort_t vt[64][72];
  const int bx = blockIdx.x;
  const int h = bx & 15, lt = (bx >> 4) & 31, b = bx >> 9;
  const int t = threadIdx.x, lr = t >> 2, s = t & 3, d0 = s * 16;
  const int lg = lt * 64 + lr;
  const int bh = b * NH + h;
  const ushort_t* rowp = qkv + ((size_t)(b * SEQ + lg) * N3) + h * HD + d0;

  ushort_t qraw[16], kraw[16], vraw[16];
  *reinterpret_cast<uint4*>(&qraw[0]) = *reinterpret_cast<const uint4*>(rowp);
  *reinterpret_cast<uint4*>(&qraw[8]) = *reinterpret_cast<const uint4*>(rowp + 8);
  *reinterpret_cast<uint4*>(&kraw[0]) = *reinterpret_cast<const uint4*>(rowp + DIM);
  *reinterpret_cast<uint4*>(&kraw[8]) = *reinterpret_cast<const uint4*>(rowp + DIM + 8);
  *reinterpret_cast<uint4*>(&vraw[0]) = *reinterpret_cast<const uint4*>(rowp + 2 * DIM);
  *reinterpret_cast<uint4*>(&vraw[8]) = *reinterpret_cast<const uint4*>(rowp + 2 * DIM + 8);
  float4 qs4[4], ks4[4];
#pragma unroll
  for (int u = 0; u < 4; ++u) {
    qs4[u] = *reinterpret_cast<const float4*>(qs + d0 + u * 4);
    ks4[u] = *reinterpret_cast<const float4*>(ksc + d0 + u * 4);
  }
  const float* sq_ = reinterpret_cast<const float*>(qs4);
  const float* sk_ = reinterpret_cast<const float*>(ks4);
  float vq[16], vk[16];
#pragma unroll
  for (int j = 0; j < 16; ++j) { vq[j] = bf2f(qraw[j]); vk[j] = bf2f(kraw[j]); }

  float sq = 0.f, sk = 0.f;
#pragma unroll
  for (int j = 0; j < 16; ++j) { sq = fmaf(vq[j], vq[j], sq); sk = fmaf(vk[j], vk[j], sk); }
  sq += __shfl_xor(sq, 1); sq += __shfl_xor(sq, 2);
  sk += __shfl_xor(sk, 1); sk += __shfl_xor(sk, 2);
  float rq = rsqrtf(sq * (1.f / HD) + 1e-6f);
  float rk = rsqrtf(sk * (1.f / HD) + 1e-6f);

  float4 c4[2], s4[2];
  const float* tc = tab + (size_t)lg * 32 + s * 8;
  const float* ts = tab + (size_t)SEQ * 32 + (size_t)lg * 32 + s * 8;
  c4[0] = *reinterpret_cast<const float4*>(tc);
  c4[1] = *reinterpret_cast<const float4*>(tc + 4);
  s4[0] = *reinterpret_cast<const float4*>(ts);
  s4[1] = *reinterpret_cast<const float4*>(ts + 4);
  const float* cj = reinterpret_cast<const float*>(c4);
  const float* sj = reinterpret_cast<const float*>(s4);

  uint uq[8], uk[8], uv[8];
#pragma unroll
  for (int j = 0; j < 8; ++j) {
    float qe = vq[2*j] * rq * sq_[2*j], qo = vq[2*j+1] * rq * sq_[2*j+1];
    float ke = vk[2*j] * rk * sk_[2*j], ko = vk[2*j+1] * rk * sk_[2*j+1];
    float c = cj[j], sn = sj[j];
    uq[j] = pack_bf16((qe * c - qo * sn) * QS, (qe * sn + qo * c) * QS);
    uk[j] = pack_bf16(ke * c - ko * sn, ke * sn + ko * c);
    uv[j] = (uint)vraw[2*j] | ((uint)vraw[2*j+1] << 16);
  }
  ushort_t* qp = qT + ((size_t)bh * SEQ + lg) * HD + d0;
  ushort_t* kp = kT + ((size_t)bh * SEQ + lg) * HD + d0;
  reinterpret_cast<uint4*>(qp)[0] = *reinterpret_cast<uint4*>(&uq[0]);
  reinterpret_cast<uint4*>(qp)[1] = *reinterpret_cast<uint4*>(&uq[4]);
  reinterpret_cast<uint4*>(kp)[0] = *reinterpret_cast<uint4*>(&uk[0]);
  reinterpret_cast<uint4*>(kp)[1] = *reinterpret_cast<uint4*>(&uk[4]);
#pragma unroll
  for (int j = 0; j < 16; ++j)
    vt[d0 + j][lr] = (ushort_t)((j & 1) ? (uv[j >> 1] >> 16) : (uv[j >> 1] & 0xffff));
  __syncthreads();
  const int drow = t >> 2, lc = (t & 3) * 16;
  ushort_t* vp = vT + ((size_t)bh * HD + drow) * SEQ + lt * 64 + lc;
  reinterpret_cast<uint4*>(vp)[0] = *reinterpret_cast<const uint4*>(&vt[drow][lc]);
  reinterpret_cast<uint4*>(vp)[1] = *reinterpret_cast<const uint4*>(&vt[drow][lc + 8]);
}

// ---------------- K3: bf16 MFMA block-causal flash attention -----------------
// Pair-balanced: block p handles q-tiles (15-p, p) -> every block = 36 phases.
// 3-buffer pipeline w/ counted vmcnt: stage(t+2) in flight across barrier.
__global__ __launch_bounds__(256) void attn_mfma_kernel(
    const ushort_t* __restrict__ qT, const ushort_t* __restrict__ kT,
    const ushort_t* __restrict__ vT, ushort_t* __restrict__ ahi,
    ushort_t* __restrict__ alo) {
  __shared__ __align__(16) char smem[65536];   // 3x16K KV bufs + 16K P
  const int tid = threadIdx.x;
  const int l  = tid & 63, w4 = tid >> 6;
  const int lm = l & 15, lw = l >> 4, l7 = l & 7, l3 = l >> 3;
  const int bh = blockIdx.y, b = bh >> 4, h = bh & 15;
  const int p = blockIdx.x;
  const int qbA = 15 - p, qbB = p;
  const int nkbA = ((qbA >> 1) + 1) * 4;       // 20..32
  const int nkbB = ((qbB >> 1) + 1) * 4;       // 4..16 (prefix of A's range)

  bf16x8 qf[2][2][2];                          // [tile][qm][ks]
#pragma unroll
  for (int tq = 0; tq < 2; ++tq) {
    const size_t qrow0 = (size_t)bh * SEQ + (tq ? qbB : qbA) * 128 + w4 * 32;
#pragma unroll
    for (int qm = 0; qm < 2; ++qm)
#pragma unroll
      for (int ks = 0; ks < 2; ++ks)
        qf[tq][qm][ks] = *reinterpret_cast<const bf16x8*>(
            qT + (qrow0 + qm * 16 + lm) * HD + lw * 8 + ks * 32);
  }

  const char* kTb = reinterpret_cast<const char*>(kT + (size_t)bh * SEQ * HD);
  const char* vTb = reinterpret_cast<const char*>(vT + (size_t)bh * HD * SEQ);
  const uint rloc = w4 * 8 + l3;
  const uint csrc = (uint)((l7 ^ l3) << 4);
  char* Pbase = smem + 49152 + w4 * 4096;

  float l_acc[2][2] = {};
  f32x4 oacc[2][2][4] = {};

  auto stage = [&](int kb, int buf) {
    const char* sK = kTb + ((size_t)(kb * 64) + rloc) * 128 + csrc;
    const char* sV = vTb + (size_t)rloc * (SEQ * 2) + (size_t)kb * 128 + csrc;
    char* dK = smem + buf * 16384 + w4 * 1024;
    char* dV = dK + 8192;
    gload16(sK, dK);
    gload16(sK + 4096, dK + 4096);
    gload16(sV, dV);
    gload16(sV + (size_t)32 * SEQ * 2, dV + 4096);
  };

  // phase: one q-tile against the staged k-tile. Compile-time-rooted refs so
  // accumulators stay in registers (no runtime-indexed ext_vector arrays).
  auto phase = [&](const bf16x8 (&qft)[2][2], float (&lat)[2],
                   f32x4 (&oat)[2][4], const char* Kb, const char* Vb) {
    f32x4 st[2][4] = {};
#pragma unroll
    for (int ks = 0; ks < 2; ++ks)
#pragma unroll
      for (int g = 0; g < 4; ++g) {
        bf16x8 kf = *reinterpret_cast<const bf16x8*>(
            Kb + (g * 16 + lm) * 128 + ((lw * 16 + ks * 64) ^ (l7 << 4)));
        st[0][g] = __builtin_amdgcn_mfma_f32_16x16x32_bf16(kf, qft[0][ks], st[0][g], 0, 0, 0);
        st[1][g] = __builtin_amdgcn_mfma_f32_16x16x32_bf16(kf, qft[1][ks], st[1][g], 0, 0, 0);
      }
#pragma unroll
    for (int qm = 0; qm < 2; ++qm)
#pragma unroll
      for (int g = 0; g < 4; ++g) {
        f32x4 s4 = st[qm][g];
        float p0 = __builtin_amdgcn_exp2f(s4.x);
        float p1 = __builtin_amdgcn_exp2f(s4.y);
        float p2 = __builtin_amdgcn_exp2f(s4.z);
        float p3 = __builtin_amdgcn_exp2f(s4.w);
        lat[qm] += (p0 + p1) + (p2 + p3);
        uint off = (uint)((qm * 16 + lm) * 128 + ((g * 32 + lw * 8) ^ (l7 << 4)));
        *reinterpret_cast<uint*>(Pbase + off)     = pack_bf16(p0, p1);
        *reinterpret_cast<uint*>(Pbase + off + 4) = pack_bf16(p2, p3);
      }
    bf16x8 pf[2][2];
#pragma unroll
    for (int qm = 0; qm < 2; ++qm)
#pragma unroll
      for (int ks = 0; ks < 2; ++ks)
        pf[qm][ks] = *reinterpret_cast<const bf16x8*>(
            Pbase + (qm * 16 + lm) * 128 + ((lw * 16 + ks * 64) ^ (l7 << 4)));
#pragma unroll
    for (int ks = 0; ks < 2; ++ks)
#pragma unroll
      for (int dn = 0; dn < 4; ++dn) {
        bf16x8 vf = *reinterpret_cast<const bf16x8*>(
            Vb + (dn * 16 + lm) * 128 + ((lw * 16 + ks * 64) ^ (l7 << 4)));
        oat[0][dn] = __builtin_amdgcn_mfma_f32_16x16x32_bf16(vf, pf[0][ks], oat[0][dn], 0, 0, 0);
        oat[1][dn] = __builtin_amdgcn_mfma_f32_16x16x32_bf16(vf, pf[1][ks], oat[1][dn], 0, 0, 0);
      }
  };

  stage(0, 0);
  stage(1, 1);

  for (int kb = 0; kb < nkbA; ++kb) {
    const int buf = kb % 3;
    if (kb + 1 < nkbA) asm volatile("s_waitcnt vmcnt(4)" ::: "memory");
    else               asm volatile("s_waitcnt vmcnt(0)" ::: "memory");
    __builtin_amdgcn_s_barrier();
    __builtin_amdgcn_sched_barrier(0);
    if (kb + 2 < nkbA) stage(kb + 2, (kb + 2) % 3);
    const char* Kb = smem + buf * 16384;
    const char* Vb = Kb + 8192;
    phase(qf[0], l_acc[0], oacc[0], Kb, Vb);
    if (kb < nkbB) phase(qf[1], l_acc[1], oacc[1], Kb, Vb);
  }

  // epilogue: finish row sums, normalize, emit hi/lo split-bf16
#pragma unroll
  for (int tq = 0; tq < 2; ++tq) {
    const int qb = tq ? qbB : qbA;
#pragma unroll
    for (int qm = 0; qm < 2; ++qm) {
      float ls = (tq ? l_acc[1] : l_acc[0])[qm];
      ls += __shfl_xor(ls, 16);
      ls += __shfl_xor(ls, 32);
      float inv = 1.f / ls;
      const int qg = qb * 128 + w4 * 32 + qm * 16 + lm;
#pragma unroll
      for (int dn = 0; dn < 4; ++dn) {
        f32x4 o = (tq ? oacc[1] : oacc[0])[qm][dn];
        o *= inv;
        ushort_t hh[4], ll[4];
#pragma unroll
        for (int j = 0; j < 4; ++j) {
          hh[j] = f2bf(o[j]);
          ll[j] = f2bf(o[j] - bf2f(hh[j]));
        }
        size_t off = ((size_t)b * SEQ + qg) * DIM + h * HD + dn * 16 + lw * 4;
        uint2 uh{(uint)hh[0] | ((uint)hh[1] << 16), (uint)hh[2] | ((uint)hh[3] << 16)};
        uint2 ul{(uint)ll[0] | ((uint)ll[1] << 16), (uint)ll[2] | ((uint)ll[3] << 16)};
        *reinterpret_cast<uint2*>(&ahi[off]) = uh;
        *reinterpret_cast<uint2*>(&alo[off]) = ul;
      }
    }
  }
}

// ---------------- launch -----------------------------------------------------
extern "C" void kernel_launch(void* const* d_in, const int* in_sizes, int n_in,
                              void* d_out, int out_size, void* d_ws, size_t ws_size,
                              hipStream_t stream) {
  const float* x       = (const float*)d_in[0];
  const float* Wqkv    = (const float*)d_in[1];
  const float* Wout    = (const float*)d_in[2];
  const float* q_scale = (const float*)d_in[3];
  const float* k_scale = (const float*)d_in[4];
  float* out = (float*)d_out;

  char* ws = (char*)d_ws;
  ushort_t* qkv = (ushort_t*)ws;                           // 25.2 MB bf16
  ushort_t* attn_hi = (ushort_t*)ws;                       // reuse qkv region
  ushort_t* attn_lo = attn_hi + (size_t)MROW * DIM;
  size_t off = (size_t)MROW * N3 * 2;
  ushort_t* qT = (ushort_t*)(ws + off); off += (size_t)NB * NH * SEQ * HD * 2;
  ushort_t* kT = (ushort_t*)(ws + off); off += (size_t)NB * NH * SEQ * HD * 2;
  ushort_t* vT = (ushort_t*)(ws + off); off += (size_t)NB * NH * SEQ * HD * 2;
  float* tab   = (float*)(ws + off);    off += (size_t)SEQ * 64 * 4;
  ushort_t* xh  = (ushort_t*)(ws + off); off += (size_t)MROW * DIM * 2;
  ushort_t* wqh = (ushort_t*)(ws + off); off += (size_t)N3 * DIM * 2;
  ushort_t* woh = (ushort_t*)(ws + off); off += (size_t)DIM * DIM * 2;
  ushort_t* wol = (ushort_t*)(ws + off);

  rope_table_kernel<<<dim3(SEQ * 32 / 256), dim3(256), 0, stream>>>(tab);
  cvt_bf16_kernel<<<dim3(MROW * DIM / 4 / 256), dim3(256), 0, stream>>>(x, xh, MROW * DIM / 4);
  cvt_bf16_kernel<<<dim3(N3 * DIM / 4 / 256), dim3(256), 0, stream>>>(Wqkv, wqh, N3 * DIM / 4);
  cvt_split_kernel<<<dim3(DIM * DIM / 4 / 256), dim3(256), 0, stream>>>(Wout, woh, wol, DIM * DIM / 4);
  gemm_mfma_kernel<128, false, true><<<dim3(N3 / 128, MROW / 128), dim3(256), 0, stream>>>(
      xh, nullptr, wqh, nullptr, qkv, N3, DIM);
  qkv_post_kernel<<<dim3(NB * 32 * NH), dim3(256), 0, stream>>>(qkv, q_scale, k_scale, tab, qT, kT, vT);
  attn_mfma_kernel<<<dim3(8, NB * NH), dim3(256), 0, stream>>>(qT, kT, vT, attn_hi, attn_lo);
  gemm_mfma_kernel<64, true, false><<<dim3(DIM / 128, MROW / 64), dim3(256), 0, stream>>>(
      attn_hi, attn_lo, woh, wol, out, DIM, DIM);
}

// Round 6
// 143.465 us; speedup vs baseline: 9.5563x; 1.0327x over previous
//
#include <hip/hip_runtime.h>
#include <hip/hip_bf16.h>
#include <cstddef>

typedef unsigned int uint;
typedef unsigned short ushort_t;
typedef __attribute__((ext_vector_type(8))) short bf16x8;
typedef __attribute__((ext_vector_type(4))) float f32x4;

constexpr int NB   = 2;
constexpr int NP   = 256;
constexpr int DIM  = 1024;
constexpr int NH   = 16;
constexpr int HD   = 64;
constexpr int SEQ  = 2048;
constexpr int MROW = NB * SEQ;      // 4096
constexpr int N3   = 3 * DIM;       // 3072
// softmax in base-2: fold hd^-0.5 * log2(e) into q
constexpr float QS = 0.125f * 1.4426950408889634f;

__device__ __forceinline__ ushort_t f2bf(float x) {
  uint u = __builtin_bit_cast(uint, x);
  u = (u + 0x7fff + ((u >> 16) & 1)) >> 16;   // round-to-nearest-even
  return (ushort_t)u;
}
__device__ __forceinline__ uint pack_bf16(float a, float b) {
  __hip_bfloat162 h = __float22bfloat162_rn(float2{a, b});
  uint u; __builtin_memcpy(&u, &h, 4);        // v_cvt_pk_bf16_f32
  return u;
}
__device__ __forceinline__ float bf2f(ushort_t h) {
  return __builtin_bit_cast(float, (uint)h << 16);
}

__device__ __forceinline__ void gload16(const void* g, void* l) {
  __builtin_amdgcn_global_load_lds((const __attribute__((address_space(1))) uint*)g,
                                   (__attribute__((address_space(3))) uint*)l, 16, 0, 0);
}

// ---------------- K0: RoPE cos/sin table ------------------------------------
__global__ __launch_bounds__(256) void rope_table_kernel(float* __restrict__ tab) {
  int idx = blockIdx.x * 256 + threadIdx.x;
  if (idx >= SEQ * 32) return;
  int l = idx >> 5, i = idx & 31;
  float j = (float)(i & 15);
  float invf = exp2f(-j * (13.287712379549449f / 16.f));
  float pos = (i < 16) ? (float)(l >> 8) : (float)(l & (NP - 1));
  float ang = pos * invf;
  tab[idx]            = cosf(ang);
  tab[SEQ * 32 + idx] = sinf(ang);
}

// ---------------- conversions ------------------------------------------------
__global__ __launch_bounds__(256) void cvt_bf16_kernel(
    const float* __restrict__ s, ushort_t* __restrict__ d, int n4) {
  int i = blockIdx.x * 256 + threadIdx.x;
  if (i >= n4) return;
  float4 v = reinterpret_cast<const float4*>(s)[i];
  uint2 o; o.x = pack_bf16(v.x, v.y); o.y = pack_bf16(v.z, v.w);
  reinterpret_cast<uint2*>(d)[i] = o;
}

__global__ __launch_bounds__(256) void cvt_split_kernel(
    const float* __restrict__ s, ushort_t* __restrict__ hi,
    ushort_t* __restrict__ lo, int n4) {
  int i = blockIdx.x * 256 + threadIdx.x;
  if (i >= n4) return;
  float4 v = reinterpret_cast<const float4*>(s)[i];
  float f[4] = {v.x, v.y, v.z, v.w};
  ushort_t h[4], l[4];
#pragma unroll
  for (int j = 0; j < 4; ++j) {
    h[j] = f2bf(f[j]);
    l[j] = f2bf(f[j] - bf2f(h[j]));
  }
  uint2 oh{(uint)h[0] | ((uint)h[1] << 16), (uint)h[2] | ((uint)h[3] << 16)};
  uint2 ol{(uint)l[0] | ((uint)l[1] << 16), (uint)l[2] | ((uint)l[3] << 16)};
  reinterpret_cast<uint2*>(hi)[i] = oh;
  reinterpret_cast<uint2*>(lo)[i] = ol;
}

// ---------------- bf16 MFMA GEMM: C[M][N] = A[M][K] * B[N][K]^T --------------
template<int BM, bool SPLIT, bool BF16OUT>
__global__ __launch_bounds__(256) void gemm_mfma_kernel(
    const ushort_t* __restrict__ Ah_, const ushort_t* __restrict__ Al_,
    const ushort_t* __restrict__ Bh_, const ushort_t* __restrict__ Bl_,
    void* __restrict__ Cv, int N, int K) {
  constexpr int MF = BM / 32;               // m-frags per wave
  constexpr int REG = (BM + 128) * 128;     // bytes per (A,B) tile pair
  __shared__ __align__(16) char smem[(SPLIT ? 2 : 1) * REG];
  const int tid = threadIdx.x;
  const int l = tid & 63, w4 = tid >> 6;
  const int l7 = l & 7, l3 = l >> 3, lm = l & 15, lw = l >> 4;
  const int wm = w4 >> 1, wn = w4 & 1;
  const int bm = blockIdx.y * BM, bn = blockIdx.x * 128;
  const uint rloc = (uint)(w4 * 8 + l3);
  const uint csrc = (uint)((l7 ^ l3) << 4);
  const uint sw = (uint)(lm & 7);

  f32x4 acc[MF][4] = {};

  auto stageAB = [&](const ushort_t* A_, const ushort_t* B_, int dstoff, int k0) {
    const char* Ab = reinterpret_cast<const char*>(A_);
    const char* Bb = reinterpret_cast<const char*>(B_);
#pragma unroll
    for (int i = 0; i < BM / 32; ++i)
      gload16(Ab + (((size_t)(bm + i * 32 + rloc) * K + k0) << 1) + csrc,
              smem + dstoff + (i * 32 + w4 * 8) * 128);
#pragma unroll
    for (int i = 0; i < 4; ++i)
      gload16(Bb + (((size_t)(bn + i * 32 + rloc) * K + k0) << 1) + csrc,
              smem + dstoff + BM * 128 + (i * 32 + w4 * 8) * 128);
  };

  for (int k0 = 0; k0 < K; k0 += 64) {
    stageAB(Ah_, Bh_, 0, k0);
    if constexpr (SPLIT) stageAB(Al_, Bl_, REG, k0);
    __syncthreads();
    const char* As = smem;
    const char* Bs = smem + BM * 128;
    bf16x8 af[MF][2], bfr[4][2];
#pragma unroll
    for (int mi = 0; mi < MF; ++mi)
#pragma unroll
      for (int ks = 0; ks < 2; ++ks)
        af[mi][ks] = *reinterpret_cast<const bf16x8*>(
            As + (wm * (BM / 2) + mi * 16 + lm) * 128 + ((((uint)ks * 4 + lw) ^ sw) << 4));
#pragma unroll
    for (int ni = 0; ni < 4; ++ni)
#pragma unroll
      for (int ks = 0; ks < 2; ++ks)
        bfr[ni][ks] = *reinterpret_cast<const bf16x8*>(
            Bs + (wn * 64 + ni * 16 + lm) * 128 + ((((uint)ks * 4 + lw) ^ sw) << 4));
#pragma unroll
    for (int ks = 0; ks < 2; ++ks)
#pragma unroll
      for (int mi = 0; mi < MF; ++mi)
#pragma unroll
        for (int ni = 0; ni < 4; ++ni)
          acc[mi][ni] = __builtin_amdgcn_mfma_f32_16x16x32_bf16(
              af[mi][ks], bfr[ni][ks], acc[mi][ni], 0, 0, 0);
    if constexpr (SPLIT) {
      const char* As2 = smem + REG;
      const char* Bs2 = smem + REG + BM * 128;
      bf16x8 al[MF][2], bl[4][2];
#pragma unroll
      for (int mi = 0; mi < MF; ++mi)
#pragma unroll
        for (int ks = 0; ks < 2; ++ks)
          al[mi][ks] = *reinterpret_cast<const bf16x8*>(
              As2 + (wm * (BM / 2) + mi * 16 + lm) * 128 + ((((uint)ks * 4 + lw) ^ sw) << 4));
#pragma unroll
      for (int ni = 0; ni < 4; ++ni)
#pragma unroll
        for (int ks = 0; ks < 2; ++ks)
          bl[ni][ks] = *reinterpret_cast<const bf16x8*>(
              Bs2 + (wn * 64 + ni * 16 + lm) * 128 + ((((uint)ks * 4 + lw) ^ sw) << 4));
#pragma unroll
      for (int ks = 0; ks < 2; ++ks)
#pragma unroll
        for (int mi = 0; mi < MF; ++mi)
#pragma unroll
          for (int ni = 0; ni < 4; ++ni) {
            acc[mi][ni] = __builtin_amdgcn_mfma_f32_16x16x32_bf16(
                al[mi][ks], bfr[ni][ks], acc[mi][ni], 0, 0, 0);
            acc[mi][ni] = __builtin_amdgcn_mfma_f32_16x16x32_bf16(
                af[mi][ks], bl[ni][ks], acc[mi][ni], 0, 0, 0);
          }
    }
    __syncthreads();
  }
#pragma unroll
  for (int mi = 0; mi < MF; ++mi)
#pragma unroll
    for (int ni = 0; ni < 4; ++ni) {
      f32x4 a = acc[mi][ni];
      const int row0 = bm + wm * (BM / 2) + mi * 16 + lw * 4;
      const int col  = bn + wn * 64 + ni * 16 + lm;
      if constexpr (BF16OUT) {
        ushort_t* Cb = (ushort_t*)Cv;
#pragma unroll
        for (int r = 0; r < 4; ++r)
          Cb[(size_t)(row0 + r) * N + col] = f2bf(a[r]);
      } else {
        float* Cf = (float*)Cv;
#pragma unroll
        for (int r = 0; r < 4; ++r)
          Cf[(size_t)(row0 + r) * N + col] = a[r];
      }
    }
}

// ---------------- K2: RMSNorm + RoPE (bf16 in); qT/kT row-major, vT d-major --
__global__ __launch_bounds__(256) void qkv_post_kernel(
    const ushort_t* __restrict__ qkv, const float* __restrict__ qs,
    const float* __restrict__ ksc, const float* __restrict__ tab,
    ushort_t* __restrict__ qT, ushort_t* __restrict__ kT, ushort_t* __restrict__ vT) {
  __shared__ ushort_t vt[64][72];
  const int bx = blockIdx.x;
  const int h = bx & 15, lt = (bx >> 4) & 31, b = bx >> 9;
  const int t = threadIdx.x, lr = t >> 2, s = t & 3, d0 = s * 16;
  const int lg = lt * 64 + lr;
  const int bh = b * NH + h;
  const ushort_t* rowp = qkv + ((size_t)(b * SEQ + lg) * N3) + h * HD + d0;

  ushort_t qraw[16], kraw[16], vraw[16];
  *reinterpret_cast<uint4*>(&qraw[0]) = *reinterpret_cast<const uint4*>(rowp);
  *reinterpret_cast<uint4*>(&qraw[8]) = *reinterpret_cast<const uint4*>(rowp + 8);
  *reinterpret_cast<uint4*>(&kraw[0]) = *reinterpret_cast<const uint4*>(rowp + DIM);
  *reinterpret_cast<uint4*>(&kraw[8]) = *reinterpret_cast<const uint4*>(rowp + DIM + 8);
  *reinterpret_cast<uint4*>(&vraw[0]) = *reinterpret_cast<const uint4*>(rowp + 2 * DIM);
  *reinterpret_cast<uint4*>(&vraw[8]) = *reinterpret_cast<const uint4*>(rowp + 2 * DIM + 8);
  float4 qs4[4], ks4[4];
#pragma unroll
  for (int u = 0; u < 4; ++u) {
    qs4[u] = *reinterpret_cast<const float4*>(qs + d0 + u * 4);
    ks4[u] = *reinterpret_cast<const float4*>(ksc + d0 + u * 4);
  }
  const float* sq_ = reinterpret_cast<const float*>(qs4);
  const float* sk_ = reinterpret_cast<const float*>(ks4);
  float vq[16], vk[16];
#pragma unroll
  for (int j = 0; j < 16; ++j) { vq[j] = bf2f(qraw[j]); vk[j] = bf2f(kraw[j]); }

  float sq = 0.f, sk = 0.f;
#pragma unroll
  for (int j = 0; j < 16; ++j) { sq = fmaf(vq[j], vq[j], sq); sk = fmaf(vk[j], vk[j], sk); }
  sq += __shfl_xor(sq, 1); sq += __shfl_xor(sq, 2);
  sk += __shfl_xor(sk, 1); sk += __shfl_xor(sk, 2);
  float rq = rsqrtf(sq * (1.f / HD) + 1e-6f);
  float rk = rsqrtf(sk * (1.f / HD) + 1e-6f);

  float4 c4[2], s4[2];
  const float* tc = tab + (size_t)lg * 32 + s * 8;
  const float* ts = tab + (size_t)SEQ * 32 + (size_t)lg * 32 + s * 8;
  c4[0] = *reinterpret_cast<const float4*>(tc);
  c4[1] = *reinterpret_cast<const float4*>(tc + 4);
  s4[0] = *reinterpret_cast<const float4*>(ts);
  s4[1] = *reinterpret_cast<const float4*>(ts + 4);
  const float* cj = reinterpret_cast<const float*>(c4);
  const float* sj = reinterpret_cast<const float*>(s4);

  uint uq[8], uk[8], uv[8];
#pragma unroll
  for (int j = 0; j < 8; ++j) {
    float qe = vq[2*j] * rq * sq_[2*j], qo = vq[2*j+1] * rq * sq_[2*j+1];
    float ke = vk[2*j] * rk * sk_[2*j], ko = vk[2*j+1] * rk * sk_[2*j+1];
    float c = cj[j], sn = sj[j];
    uq[j] = pack_bf16((qe * c - qo * sn) * QS, (qe * sn + qo * c) * QS);
    uk[j] = pack_bf16(ke * c - ko * sn, ke * sn + ko * c);
    uv[j] = (uint)vraw[2*j] | ((uint)vraw[2*j+1] << 16);
  }
  ushort_t* qp = qT + ((size_t)bh * SEQ + lg) * HD + d0;
  ushort_t* kp = kT + ((size_t)bh * SEQ + lg) * HD + d0;
  reinterpret_cast<uint4*>(qp)[0] = *reinterpret_cast<uint4*>(&uq[0]);
  reinterpret_cast<uint4*>(qp)[1] = *reinterpret_cast<uint4*>(&uq[4]);
  reinterpret_cast<uint4*>(kp)[0] = *reinterpret_cast<uint4*>(&uk[0]);
  reinterpret_cast<uint4*>(kp)[1] = *reinterpret_cast<uint4*>(&uk[4]);
#pragma unroll
  for (int j = 0; j < 16; ++j)
    vt[d0 + j][lr] = (ushort_t)((j & 1) ? (uv[j >> 1] >> 16) : (uv[j >> 1] & 0xffff));
  __syncthreads();
  const int drow = t >> 2, lc = (t & 3) * 16;
  ushort_t* vp = vT + ((size_t)bh * HD + drow) * SEQ + lt * 64 + lc;
  reinterpret_cast<uint4*>(vp)[0] = *reinterpret_cast<const uint4*>(&vt[drow][lc]);
  reinterpret_cast<uint4*>(vp)[1] = *reinterpret_cast<const uint4*>(&vt[drow][lc + 8]);
}

// ---------------- K3: bf16 MFMA block-causal flash attention -----------------
// 8 waves: group0 (waves 0-3) even k-tiles, group1 (waves 4-7) odd k-tiles.
// No-max softmax => k-split partials are exactly additive; merged via LDS.
// Pair-balanced: block p handles q-tiles (15-p, p) = 36 phases = 18 iters.
// Per-group 3-buffer counted-vmcnt pipeline. LDS: 6x16K KV + 8x4K P = 128K.
__global__ __launch_bounds__(512) void attn_mfma_kernel(
    const ushort_t* __restrict__ qT, const ushort_t* __restrict__ kT,
    const ushort_t* __restrict__ vT, ushort_t* __restrict__ ahi,
    ushort_t* __restrict__ alo) {
  __shared__ __align__(16) char smem[131072];
  const int tid = threadIdx.x;
  const int l  = tid & 63, w8 = tid >> 6;
  const int grp = w8 >> 2, w4 = w8 & 3;
  const int lm = l & 15, lw = l >> 4, l7 = l & 7, l3 = l >> 3;
  const int bh = blockIdx.y, b = bh >> 4, h = bh & 15;
  const int p = blockIdx.x;
  const int qbA = 15 - p, qbB = p;
  const int nkbA = ((qbA >> 1) + 1) * 4;       // 20..32 (even)
  const int nkbB = ((qbB >> 1) + 1) * 4;       // 4..16  (prefix of A's range)
  const int iters  = nkbA >> 1;
  const int bIters = nkbB >> 1;

  bf16x8 qf[2][2][2];                          // [tile][qm][ks]
#pragma unroll
  for (int tq = 0; tq < 2; ++tq) {
    const size_t qrow0 = (size_t)bh * SEQ + (tq ? qbB : qbA) * 128 + w4 * 32;
#pragma unroll
    for (int qm = 0; qm < 2; ++qm)
#pragma unroll
      for (int ks = 0; ks < 2; ++ks)
        qf[tq][qm][ks] = *reinterpret_cast<const bf16x8*>(
            qT + (qrow0 + qm * 16 + lm) * HD + lw * 8 + ks * 32);
  }

  const char* kTb = reinterpret_cast<const char*>(kT + (size_t)bh * SEQ * HD);
  const char* vTb = reinterpret_cast<const char*>(vT + (size_t)bh * HD * SEQ);
  const uint rloc = w4 * 8 + l3;
  const uint csrc = (uint)((l7 ^ l3) << 4);
  char* Pbase = smem + 98304 + w8 * 4096;

  float l_acc[2][2] = {};
  f32x4 oacc[2][2][4] = {};

  auto stage = [&](int kb, int bufidx) {
    const char* sK = kTb + ((size_t)(kb * 64) + rloc) * 128 + csrc;
    const char* sV = vTb + (size_t)rloc * (SEQ * 2) + (size_t)kb * 128 + csrc;
    char* dK = smem + (grp * 3 + bufidx) * 16384 + w4 * 1024;
    char* dV = dK + 8192;
    gload16(sK, dK);
    gload16(sK + 4096, dK + 4096);
    gload16(sV, dV);
    gload16(sV + (size_t)32 * SEQ * 2, dV + 4096);
  };

  auto phase = [&](const bf16x8 (&qft)[2][2], float (&lat)[2],
                   f32x4 (&oat)[2][4], const char* Kb, const char* Vb) {
    f32x4 st[2][4] = {};
#pragma unroll
    for (int ks = 0; ks < 2; ++ks)
#pragma unroll
      for (int g = 0; g < 4; ++g) {
        bf16x8 kf = *reinterpret_cast<const bf16x8*>(
            Kb + (g * 16 + lm) * 128 + ((lw * 16 + ks * 64) ^ (l7 << 4)));
        st[0][g] = __builtin_amdgcn_mfma_f32_16x16x32_bf16(kf, qft[0][ks], st[0][g], 0, 0, 0);
        st[1][g] = __builtin_amdgcn_mfma_f32_16x16x32_bf16(kf, qft[1][ks], st[1][g], 0, 0, 0);
      }
#pragma unroll
    for (int qm = 0; qm < 2; ++qm)
#pragma unroll
      for (int g = 0; g < 4; ++g) {
        f32x4 s4 = st[qm][g];
        float p0 = __builtin_amdgcn_exp2f(s4.x);
        float p1 = __builtin_amdgcn_exp2f(s4.y);
        float p2 = __builtin_amdgcn_exp2f(s4.z);
        float p3 = __builtin_amdgcn_exp2f(s4.w);
        lat[qm] += (p0 + p1) + (p2 + p3);
        uint off = (uint)((qm * 16 + lm) * 128 + ((g * 32 + lw * 8) ^ (l7 << 4)));
        *reinterpret_cast<uint*>(Pbase + off)     = pack_bf16(p0, p1);
        *reinterpret_cast<uint*>(Pbase + off + 4) = pack_bf16(p2, p3);
      }
    bf16x8 pf[2][2];
#pragma unroll
    for (int qm = 0; qm < 2; ++qm)
#pragma unroll
      for (int ks = 0; ks < 2; ++ks)
        pf[qm][ks] = *reinterpret_cast<const bf16x8*>(
            Pbase + (qm * 16 + lm) * 128 + ((lw * 16 + ks * 64) ^ (l7 << 4)));
#pragma unroll
    for (int ks = 0; ks < 2; ++ks)
#pragma unroll
      for (int dn = 0; dn < 4; ++dn) {
        bf16x8 vf = *reinterpret_cast<const bf16x8*>(
            Vb + (dn * 16 + lm) * 128 + ((lw * 16 + ks * 64) ^ (l7 << 4)));
        oat[0][dn] = __builtin_amdgcn_mfma_f32_16x16x32_bf16(vf, pf[0][ks], oat[0][dn], 0, 0, 0);
        oat[1][dn] = __builtin_amdgcn_mfma_f32_16x16x32_bf16(vf, pf[1][ks], oat[1][dn], 0, 0, 0);
      }
  };

  // prologue: group g stages its tiles #0 (kb=g) and #1 (kb=g+2)
  stage(grp, 0);
  stage(grp + 2, 1);

  for (int i = 0; i < iters; ++i) {
    const int bufidx = i % 3;
    if (i + 1 < iters) asm volatile("s_waitcnt vmcnt(4)" ::: "memory");
    else               asm volatile("s_waitcnt vmcnt(0)" ::: "memory");
    __builtin_amdgcn_s_barrier();
    __builtin_amdgcn_sched_barrier(0);
    if (i + 2 < iters) stage(2 * (i + 2) + grp, (i + 2) % 3);
    const char* Kb = smem + (grp * 3 + bufidx) * 16384;
    const char* Vb = Kb + 8192;
    phase(qf[0], l_acc[0], oacc[0], Kb, Vb);
    if (i < bIters) phase(qf[1], l_acc[1], oacc[1], Kb, Vb);
  }

  // merge group partials: group1 -> LDS (KV region now dead), group0 adds.
  __syncthreads();
  if (grp == 1) {
    char* dst = smem + w4 * 16384 + l * 256;
#pragma unroll
    for (int tq = 0; tq < 2; ++tq)
#pragma unroll
      for (int qm = 0; qm < 2; ++qm)
#pragma unroll
        for (int dn = 0; dn < 4; ++dn)
          *reinterpret_cast<f32x4*>(dst + ((tq * 2 + qm) * 4 + dn) * 16) = oacc[tq][qm][dn];
    float4 lv{l_acc[0][0], l_acc[0][1], l_acc[1][0], l_acc[1][1]};
    *reinterpret_cast<float4*>(smem + 65536 + (w4 * 64 + l) * 16) = lv;
  }
  __syncthreads();
  if (grp == 0) {
    const char* src = smem + w4 * 16384 + l * 256;
#pragma unroll
    for (int tq = 0; tq < 2; ++tq)
#pragma unroll
      for (int qm = 0; qm < 2; ++qm)
#pragma unroll
        for (int dn = 0; dn < 4; ++dn)
          oacc[tq][qm][dn] += *reinterpret_cast<const f32x4*>(src + ((tq * 2 + qm) * 4 + dn) * 16);
    float4 lv = *reinterpret_cast<const float4*>(smem + 65536 + (w4 * 64 + l) * 16);
    l_acc[0][0] += lv.x; l_acc[0][1] += lv.y; l_acc[1][0] += lv.z; l_acc[1][1] += lv.w;

#pragma unroll
    for (int tq = 0; tq < 2; ++tq) {
      const int qb = tq ? qbB : qbA;
#pragma unroll
      for (int qm = 0; qm < 2; ++qm) {
        float ls = (tq ? l_acc[1] : l_acc[0])[qm];
        ls += __shfl_xor(ls, 16);
        ls += __shfl_xor(ls, 32);
        float inv = 1.f / ls;
        const int qg = qb * 128 + w4 * 32 + qm * 16 + lm;
#pragma unroll
        for (int dn = 0; dn < 4; ++dn) {
          f32x4 o = (tq ? oacc[1] : oacc[0])[qm][dn];
          o *= inv;
          ushort_t hh[4], ll[4];
#pragma unroll
          for (int j = 0; j < 4; ++j) {
            hh[j] = f2bf(o[j]);
            ll[j] = f2bf(o[j] - bf2f(hh[j]));
          }
          size_t off = ((size_t)b * SEQ + qg) * DIM + h * HD + dn * 16 + lw * 4;
          uint2 uh{(uint)hh[0] | ((uint)hh[1] << 16), (uint)hh[2] | ((uint)hh[3] << 16)};
          uint2 ul{(uint)ll[0] | ((uint)ll[1] << 16), (uint)ll[2] | ((uint)ll[3] << 16)};
          *reinterpret_cast<uint2*>(&ahi[off]) = uh;
          *reinterpret_cast<uint2*>(&alo[off]) = ul;
        }
      }
    }
  }
}

// ---------------- launch -----------------------------------------------------
extern "C" void kernel_launch(void* const* d_in, const int* in_sizes, int n_in,
                              void* d_out, int out_size, void* d_ws, size_t ws_size,
                              hipStream_t stream) {
  const float* x       = (const float*)d_in[0];
  const float* Wqkv    = (const float*)d_in[1];
  const float* Wout    = (const float*)d_in[2];
  const float* q_scale = (const float*)d_in[3];
  const float* k_scale = (const float*)d_in[4];
  float* out = (float*)d_out;

  char* ws = (char*)d_ws;
  ushort_t* qkv = (ushort_t*)ws;                           // 25.2 MB bf16
  ushort_t* attn_hi = (ushort_t*)ws;                       // reuse qkv region
  ushort_t* attn_lo = attn_hi + (size_t)MROW * DIM;
  size_t off = (size_t)MROW * N3 * 2;
  ushort_t* qT = (ushort_t*)(ws + off); off += (size_t)NB * NH * SEQ * HD * 2;
  ushort_t* kT = (ushort_t*)(ws + off); off += (size_t)NB * NH * SEQ * HD * 2;
  ushort_t* vT = (ushort_t*)(ws + off); off += (size_t)NB * NH * SEQ * HD * 2;
  float* tab   = (float*)(ws + off);    off += (size_t)SEQ * 64 * 4;
  ushort_t* xh  = (ushort_t*)(ws + off); off += (size_t)MROW * DIM * 2;
  ushort_t* wqh = (ushort_t*)(ws + off); off += (size_t)N3 * DIM * 2;
  ushort_t* woh = (ushort_t*)(ws + off); off += (size_t)DIM * DIM * 2;
  ushort_t* wol = (ushort_t*)(ws + off);

  rope_table_kernel<<<dim3(SEQ * 32 / 256), dim3(256), 0, stream>>>(tab);
  cvt_bf16_kernel<<<dim3(MROW * DIM / 4 / 256), dim3(256), 0, stream>>>(x, xh, MROW * DIM / 4);
  cvt_bf16_kernel<<<dim3(N3 * DIM / 4 / 256), dim3(256), 0, stream>>>(Wqkv, wqh, N3 * DIM / 4);
  cvt_split_kernel<<<dim3(DIM * DIM / 4 / 256), dim3(256), 0, stream>>>(Wout, woh, wol, DIM * DIM / 4);
  gemm_mfma_kernel<128, false, true><<<dim3(N3 / 128, MROW / 128), dim3(256), 0, stream>>>(
      xh, nullptr, wqh, nullptr, qkv, N3, DIM);
  qkv_post_kernel<<<dim3(NB * 32 * NH), dim3(256), 0, stream>>>(qkv, q_scale, k_scale, tab, qT, kT, vT);
  attn_mfma_kernel<<<dim3(8, NB * NH), dim3(512), 0, stream>>>(qT, kT, vT, attn_hi, attn_lo);
  gemm_mfma_kernel<64, true, false><<<dim3(DIM / 128, MROW / 64), dim3(256), 0, stream>>>(
      attn_hi, attn_lo, woh, wol, out, DIM, DIM);
}

// Round 7
// 132.782 us; speedup vs baseline: 10.3252x; 1.0805x over previous
//
#include <hip/hip_runtime.h>
#include <hip/hip_bf16.h>
#include <cstddef>

typedef unsigned int uint;
typedef unsigned short ushort_t;
typedef __attribute__((ext_vector_type(8))) short bf16x8;
typedef __attribute__((ext_vector_type(4))) float f32x4;

constexpr int NB   = 2;
constexpr int NP   = 256;
constexpr int DIM  = 1024;
constexpr int NH   = 16;
constexpr int HD   = 64;
constexpr int SEQ  = 2048;
constexpr int MROW = NB * SEQ;      // 4096
constexpr int N3   = 3 * DIM;       // 3072
// softmax in base-2: fold hd^-0.5 * log2(e) into q
constexpr float QS = 0.125f * 1.4426950408889634f;

__device__ __forceinline__ ushort_t f2bf(float x) {
  uint u = __builtin_bit_cast(uint, x);
  u = (u + 0x7fff + ((u >> 16) & 1)) >> 16;   // round-to-nearest-even
  return (ushort_t)u;
}
__device__ __forceinline__ uint pack_bf16(float a, float b) {
  __hip_bfloat162 h = __float22bfloat162_rn(float2{a, b});
  uint u; __builtin_memcpy(&u, &h, 4);        // v_cvt_pk_bf16_f32
  return u;
}
__device__ __forceinline__ float bf2f(ushort_t h) {
  return __builtin_bit_cast(float, (uint)h << 16);
}

__device__ __forceinline__ void gload16(const void* g, void* l) {
  __builtin_amdgcn_global_load_lds((const __attribute__((address_space(1))) uint*)g,
                                   (__attribute__((address_space(3))) uint*)l, 16, 0, 0);
}

// ---------------- K0: RoPE cos/sin table ------------------------------------
__global__ __launch_bounds__(256) void rope_table_kernel(float* __restrict__ tab) {
  int idx = blockIdx.x * 256 + threadIdx.x;
  if (idx >= SEQ * 32) return;
  int l = idx >> 5, i = idx & 31;
  float j = (float)(i & 15);
  float invf = exp2f(-j * (13.287712379549449f / 16.f));
  float pos = (i < 16) ? (float)(l >> 8) : (float)(l & (NP - 1));
  float ang = pos * invf;
  tab[idx]            = cosf(ang);
  tab[SEQ * 32 + idx] = sinf(ang);
}

// ---------------- conversions ------------------------------------------------
__global__ __launch_bounds__(256) void cvt_bf16_kernel(
    const float* __restrict__ s, ushort_t* __restrict__ d, int n4) {
  int i = blockIdx.x * 256 + threadIdx.x;
  if (i >= n4) return;
  float4 v = reinterpret_cast<const float4*>(s)[i];
  uint2 o; o.x = pack_bf16(v.x, v.y); o.y = pack_bf16(v.z, v.w);
  reinterpret_cast<uint2*>(d)[i] = o;
}

__global__ __launch_bounds__(256) void cvt_split_kernel(
    const float* __restrict__ s, ushort_t* __restrict__ hi,
    ushort_t* __restrict__ lo, int n4) {
  int i = blockIdx.x * 256 + threadIdx.x;
  if (i >= n4) return;
  float4 v = reinterpret_cast<const float4*>(s)[i];
  float f[4] = {v.x, v.y, v.z, v.w};
  ushort_t h[4], l[4];
#pragma unroll
  for (int j = 0; j < 4; ++j) {
    h[j] = f2bf(f[j]);
    l[j] = f2bf(f[j] - bf2f(h[j]));
  }
  uint2 oh{(uint)h[0] | ((uint)h[1] << 16), (uint)h[2] | ((uint)h[3] << 16)};
  uint2 ol{(uint)l[0] | ((uint)l[1] << 16), (uint)l[2] | ((uint)l[3] << 16)};
  reinterpret_cast<uint2*>(hi)[i] = oh;
  reinterpret_cast<uint2*>(lo)[i] = ol;
}

// ---------------- bf16 MFMA GEMM: C[M][N] = A[M][K] * B[N][K]^T --------------
// 2-phase double-buffered: stage(t+1) issued BEFORE compute(t); single
// __syncthreads()/iter (its vmcnt(0) drain is exactly the wait for t+1).
template<int BM, bool SPLIT, bool BF16OUT>
__global__ __launch_bounds__(256) void gemm_mfma_kernel(
    const ushort_t* __restrict__ Ah_, const ushort_t* __restrict__ Al_,
    const ushort_t* __restrict__ Bh_, const ushort_t* __restrict__ Bl_,
    void* __restrict__ Cv, int N, int K) {
  constexpr int MF = BM / 32;               // m-frags per wave
  constexpr int REG = (BM + 128) * 128;     // bytes per (A,B) tile pair
  constexpr int PH  = (SPLIT ? 2 : 1) * REG; // bytes per phase
  __shared__ __align__(16) char smem[2 * PH];
  const int tid = threadIdx.x;
  const int l = tid & 63, w4 = tid >> 6;
  const int l7 = l & 7, l3 = l >> 3, lm = l & 15, lw = l >> 4;
  const int wm = w4 >> 1, wn = w4 & 1;
  const int bm = blockIdx.y * BM, bn = blockIdx.x * 128;
  const uint rloc = (uint)(w4 * 8 + l3);
  const uint csrc = (uint)((l7 ^ l3) << 4);
  const uint sw = (uint)(lm & 7);

  f32x4 acc[MF][4] = {};

  auto stageAB = [&](const ushort_t* A_, const ushort_t* B_, int dstoff, int k0) {
    const char* Ab = reinterpret_cast<const char*>(A_);
    const char* Bb = reinterpret_cast<const char*>(B_);
#pragma unroll
    for (int i = 0; i < BM / 32; ++i)
      gload16(Ab + (((size_t)(bm + i * 32 + rloc) * K + k0) << 1) + csrc,
              smem + dstoff + (i * 32 + w4 * 8) * 128);
#pragma unroll
    for (int i = 0; i < 4; ++i)
      gload16(Bb + (((size_t)(bn + i * 32 + rloc) * K + k0) << 1) + csrc,
              smem + dstoff + BM * 128 + (i * 32 + w4 * 8) * 128);
  };

  // prologue: stage tile 0 into phase 0
  stageAB(Ah_, Bh_, 0, 0);
  if constexpr (SPLIT) stageAB(Al_, Bl_, REG, 0);
  __syncthreads();

  int cur = 0;
  for (int k0 = 0; k0 < K; k0 += 64) {
    const int nxt = cur ^ 1;
    if (k0 + 64 < K) {
      stageAB(Ah_, Bh_, nxt * PH, k0 + 64);
      if constexpr (SPLIT) stageAB(Al_, Bl_, nxt * PH + REG, k0 + 64);
    }
    const char* As = smem + cur * PH;
    const char* Bs = As + BM * 128;
    bf16x8 af[MF][2], bfr[4][2];
#pragma unroll
    for (int mi = 0; mi < MF; ++mi)
#pragma unroll
      for (int ks = 0; ks < 2; ++ks)
        af[mi][ks] = *reinterpret_cast<const bf16x8*>(
            As + (wm * (BM / 2) + mi * 16 + lm) * 128 + ((((uint)ks * 4 + lw) ^ sw) << 4));
#pragma unroll
    for (int ni = 0; ni < 4; ++ni)
#pragma unroll
      for (int ks = 0; ks < 2; ++ks)
        bfr[ni][ks] = *reinterpret_cast<const bf16x8*>(
            Bs + (wn * 64 + ni * 16 + lm) * 128 + ((((uint)ks * 4 + lw) ^ sw) << 4));
#pragma unroll
    for (int ks = 0; ks < 2; ++ks)
#pragma unroll
      for (int mi = 0; mi < MF; ++mi)
#pragma unroll
        for (int ni = 0; ni < 4; ++ni)
          acc[mi][ni] = __builtin_amdgcn_mfma_f32_16x16x32_bf16(
              af[mi][ks], bfr[ni][ks], acc[mi][ni], 0, 0, 0);
    if constexpr (SPLIT) {
      const char* As2 = As + REG;
      const char* Bs2 = As2 + BM * 128;
      {  // al * bh   (al freed before bl loads -> lower reg pressure)
        bf16x8 al[MF][2];
#pragma unroll
        for (int mi = 0; mi < MF; ++mi)
#pragma unroll
          for (int ks = 0; ks < 2; ++ks)
            al[mi][ks] = *reinterpret_cast<const bf16x8*>(
                As2 + (wm * (BM / 2) + mi * 16 + lm) * 128 + ((((uint)ks * 4 + lw) ^ sw) << 4));
#pragma unroll
        for (int ks = 0; ks < 2; ++ks)
#pragma unroll
          for (int mi = 0; mi < MF; ++mi)
#pragma unroll
            for (int ni = 0; ni < 4; ++ni)
              acc[mi][ni] = __builtin_amdgcn_mfma_f32_16x16x32_bf16(
                  al[mi][ks], bfr[ni][ks], acc[mi][ni], 0, 0, 0);
      }
      {  // ah * bl
        bf16x8 bl[4][2];
#pragma unroll
        for (int ni = 0; ni < 4; ++ni)
#pragma unroll
          for (int ks = 0; ks < 2; ++ks)
            bl[ni][ks] = *reinterpret_cast<const bf16x8*>(
                Bs2 + (wn * 64 + ni * 16 + lm) * 128 + ((((uint)ks * 4 + lw) ^ sw) << 4));
#pragma unroll
        for (int ks = 0; ks < 2; ++ks)
#pragma unroll
          for (int mi = 0; mi < MF; ++mi)
#pragma unroll
            for (int ni = 0; ni < 4; ++ni)
              acc[mi][ni] = __builtin_amdgcn_mfma_f32_16x16x32_bf16(
                  af[mi][ks], bl[ni][ks], acc[mi][ni], 0, 0, 0);
      }
    }
    __syncthreads();   // drains vmcnt(0): next phase staged; cur readers done
    cur ^= 1;
  }
#pragma unroll
  for (int mi = 0; mi < MF; ++mi)
#pragma unroll
    for (int ni = 0; ni < 4; ++ni) {
      f32x4 a = acc[mi][ni];
      const int row0 = bm + wm * (BM / 2) + mi * 16 + lw * 4;
      const int col  = bn + wn * 64 + ni * 16 + lm;
      if constexpr (BF16OUT) {
        ushort_t* Cb = (ushort_t*)Cv;
#pragma unroll
        for (int r = 0; r < 4; ++r)
          Cb[(size_t)(row0 + r) * N + col] = f2bf(a[r]);
      } else {
        float* Cf = (float*)Cv;
#pragma unroll
        for (int r = 0; r < 4; ++r)
          Cf[(size_t)(row0 + r) * N + col] = a[r];
      }
    }
}

// ---------------- K2: RMSNorm + RoPE (bf16 in); qT/kT row-major, vT d-major --
__global__ __launch_bounds__(256) void qkv_post_kernel(
    const ushort_t* __restrict__ qkv, const float* __restrict__ qs,
    const float* __restrict__ ksc, const float* __restrict__ tab,
    ushort_t* __restrict__ qT, ushort_t* __restrict__ kT, ushort_t* __restrict__ vT) {
  __shared__ ushort_t vt[64][72];
  const int bx = blockIdx.x;
  const int h = bx & 15, lt = (bx >> 4) & 31, b = bx >> 9;
  const int t = threadIdx.x, lr = t >> 2, s = t & 3, d0 = s * 16;
  const int lg = lt * 64 + lr;
  const int bh = b * NH + h;
  const ushort_t* rowp = qkv + ((size_t)(b * SEQ + lg) * N3) + h * HD + d0;

  ushort_t qraw[16], kraw[16], vraw[16];
  *reinterpret_cast<uint4*>(&qraw[0]) = *reinterpret_cast<const uint4*>(rowp);
  *reinterpret_cast<uint4*>(&qraw[8]) = *reinterpret_cast<const uint4*>(rowp + 8);
  *reinterpret_cast<uint4*>(&kraw[0]) = *reinterpret_cast<const uint4*>(rowp + DIM);
  *reinterpret_cast<uint4*>(&kraw[8]) = *reinterpret_cast<const uint4*>(rowp + DIM + 8);
  *reinterpret_cast<uint4*>(&vraw[0]) = *reinterpret_cast<const uint4*>(rowp + 2 * DIM);
  *reinterpret_cast<uint4*>(&vraw[8]) = *reinterpret_cast<const uint4*>(rowp + 2 * DIM + 8);
  float4 qs4[4], ks4[4];
#pragma unroll
  for (int u = 0; u < 4; ++u) {
    qs4[u] = *reinterpret_cast<const float4*>(qs + d0 + u * 4);
    ks4[u] = *reinterpret_cast<const float4*>(ksc + d0 + u * 4);
  }
  const float* sq_ = reinterpret_cast<const float*>(qs4);
  const float* sk_ = reinterpret_cast<const float*>(ks4);
  float vq[16], vk[16];
#pragma unroll
  for (int j = 0; j < 16; ++j) { vq[j] = bf2f(qraw[j]); vk[j] = bf2f(kraw[j]); }

  float sq = 0.f, sk = 0.f;
#pragma unroll
  for (int j = 0; j < 16; ++j) { sq = fmaf(vq[j], vq[j], sq); sk = fmaf(vk[j], vk[j], sk); }
  sq += __shfl_xor(sq, 1); sq += __shfl_xor(sq, 2);
  sk += __shfl_xor(sk, 1); sk += __shfl_xor(sk, 2);
  float rq = rsqrtf(sq * (1.f / HD) + 1e-6f);
  float rk = rsqrtf(sk * (1.f / HD) + 1e-6f);

  float4 c4[2], s4[2];
  const float* tc = tab + (size_t)lg * 32 + s * 8;
  const float* ts = tab + (size_t)SEQ * 32 + (size_t)lg * 32 + s * 8;
  c4[0] = *reinterpret_cast<const float4*>(tc);
  c4[1] = *reinterpret_cast<const float4*>(tc + 4);
  s4[0] = *reinterpret_cast<const float4*>(ts);
  s4[1] = *reinterpret_cast<const float4*>(ts + 4);
  const float* cj = reinterpret_cast<const float*>(c4);
  const float* sj = reinterpret_cast<const float*>(s4);

  uint uq[8], uk[8], uv[8];
#pragma unroll
  for (int j = 0; j < 8; ++j) {
    float qe = vq[2*j] * rq * sq_[2*j], qo = vq[2*j+1] * rq * sq_[2*j+1];
    float ke = vk[2*j] * rk * sk_[2*j], ko = vk[2*j+1] * rk * sk_[2*j+1];
    float c = cj[j], sn = sj[j];
    uq[j] = pack_bf16((qe * c - qo * sn) * QS, (qe * sn + qo * c) * QS);
    uk[j] = pack_bf16(ke * c - ko * sn, ke * sn + ko * c);
    uv[j] = (uint)vraw[2*j] | ((uint)vraw[2*j+1] << 16);
  }
  ushort_t* qp = qT + ((size_t)bh * SEQ + lg) * HD + d0;
  ushort_t* kp = kT + ((size_t)bh * SEQ + lg) * HD + d0;
  reinterpret_cast<uint4*>(qp)[0] = *reinterpret_cast<uint4*>(&uq[0]);
  reinterpret_cast<uint4*>(qp)[1] = *reinterpret_cast<uint4*>(&uq[4]);
  reinterpret_cast<uint4*>(kp)[0] = *reinterpret_cast<uint4*>(&uk[0]);
  reinterpret_cast<uint4*>(kp)[1] = *reinterpret_cast<uint4*>(&uk[4]);
#pragma unroll
  for (int j = 0; j < 16; ++j)
    vt[d0 + j][lr] = (ushort_t)((j & 1) ? (uv[j >> 1] >> 16) : (uv[j >> 1] & 0xffff));
  __syncthreads();
  const int drow = t >> 2, lc = (t & 3) * 16;
  ushort_t* vp = vT + ((size_t)bh * HD + drow) * SEQ + lt * 64 + lc;
  reinterpret_cast<uint4*>(vp)[0] = *reinterpret_cast<const uint4*>(&vt[drow][lc]);
  reinterpret_cast<uint4*>(vp)[1] = *reinterpret_cast<const uint4*>(&vt[drow][lc + 8]);
}

// ---------------- K3: bf16 MFMA block-causal flash attention -----------------
// 8 waves: group0 (waves 0-3) even k-tiles, group1 (waves 4-7) odd k-tiles.
// No-max softmax => k-split partials are exactly additive; merged via LDS.
// Pair-balanced: block p handles q-tiles (15-p, p) = 36 phases = 18 iters.
// Per-group 3-buffer counted-vmcnt pipeline. LDS: 6x16K KV + 8x4K P = 128K.
__global__ __launch_bounds__(512) void attn_mfma_kernel(
    const ushort_t* __restrict__ qT, const ushort_t* __restrict__ kT,
    const ushort_t* __restrict__ vT, ushort_t* __restrict__ ahi,
    ushort_t* __restrict__ alo) {
  __shared__ __align__(16) char smem[131072];
  const int tid = threadIdx.x;
  const int l  = tid & 63, w8 = tid >> 6;
  const int grp = w8 >> 2, w4 = w8 & 3;
  const int lm = l & 15, lw = l >> 4, l7 = l & 7, l3 = l >> 3;
  const int bh = blockIdx.y, b = bh >> 4, h = bh & 15;
  const int p = blockIdx.x;
  const int qbA = 15 - p, qbB = p;
  const int nkbA = ((qbA >> 1) + 1) * 4;       // 20..32 (even)
  const int nkbB = ((qbB >> 1) + 1) * 4;       // 4..16  (prefix of A's range)
  const int iters  = nkbA >> 1;
  const int bIters = nkbB >> 1;

  bf16x8 qf[2][2][2];                          // [tile][qm][ks]
#pragma unroll
  for (int tq = 0; tq < 2; ++tq) {
    const size_t qrow0 = (size_t)bh * SEQ + (tq ? qbB : qbA) * 128 + w4 * 32;
#pragma unroll
    for (int qm = 0; qm < 2; ++qm)
#pragma unroll
      for (int ks = 0; ks < 2; ++ks)
        qf[tq][qm][ks] = *reinterpret_cast<const bf16x8*>(
            qT + (qrow0 + qm * 16 + lm) * HD + lw * 8 + ks * 32);
  }

  const char* kTb = reinterpret_cast<const char*>(kT + (size_t)bh * SEQ * HD);
  const char* vTb = reinterpret_cast<const char*>(vT + (size_t)bh * HD * SEQ);
  const uint rloc = w4 * 8 + l3;
  const uint csrc = (uint)((l7 ^ l3) << 4);
  char* Pbase = smem + 98304 + w8 * 4096;

  float l_acc[2][2] = {};
  f32x4 oacc[2][2][4] = {};

  auto stage = [&](int kb, int bufidx) {
    const char* sK = kTb + ((size_t)(kb * 64) + rloc) * 128 + csrc;
    const char* sV = vTb + (size_t)rloc * (SEQ * 2) + (size_t)kb * 128 + csrc;
    char* dK = smem + (grp * 3 + bufidx) * 16384 + w4 * 1024;
    char* dV = dK + 8192;
    gload16(sK, dK);
    gload16(sK + 4096, dK + 4096);
    gload16(sV, dV);
    gload16(sV + (size_t)32 * SEQ * 2, dV + 4096);
  };

  auto phase = [&](const bf16x8 (&qft)[2][2], float (&lat)[2],
                   f32x4 (&oat)[2][4], const char* Kb, const char* Vb) {
    f32x4 st[2][4] = {};
#pragma unroll
    for (int ks = 0; ks < 2; ++ks)
#pragma unroll
      for (int g = 0; g < 4; ++g) {
        bf16x8 kf = *reinterpret_cast<const bf16x8*>(
            Kb + (g * 16 + lm) * 128 + ((lw * 16 + ks * 64) ^ (l7 << 4)));
        st[0][g] = __builtin_amdgcn_mfma_f32_16x16x32_bf16(kf, qft[0][ks], st[0][g], 0, 0, 0);
        st[1][g] = __builtin_amdgcn_mfma_f32_16x16x32_bf16(kf, qft[1][ks], st[1][g], 0, 0, 0);
      }
#pragma unroll
    for (int qm = 0; qm < 2; ++qm)
#pragma unroll
      for (int g = 0; g < 4; ++g) {
        f32x4 s4 = st[qm][g];
        float p0 = __builtin_amdgcn_exp2f(s4.x);
        float p1 = __builtin_amdgcn_exp2f(s4.y);
        float p2 = __builtin_amdgcn_exp2f(s4.z);
        float p3 = __builtin_amdgcn_exp2f(s4.w);
        lat[qm] += (p0 + p1) + (p2 + p3);
        uint off = (uint)((qm * 16 + lm) * 128 + ((g * 32 + lw * 8) ^ (l7 << 4)));
        *reinterpret_cast<uint*>(Pbase + off)     = pack_bf16(p0, p1);
        *reinterpret_cast<uint*>(Pbase + off + 4) = pack_bf16(p2, p3);
      }
    bf16x8 pf[2][2];
#pragma unroll
    for (int qm = 0; qm < 2; ++qm)
#pragma unroll
      for (int ks = 0; ks < 2; ++ks)
        pf[qm][ks] = *reinterpret_cast<const bf16x8*>(
            Pbase + (qm * 16 + lm) * 128 + ((lw * 16 + ks * 64) ^ (l7 << 4)));
#pragma unroll
    for (int ks = 0; ks < 2; ++ks)
#pragma unroll
      for (int dn = 0; dn < 4; ++dn) {
        bf16x8 vf = *reinterpret_cast<const bf16x8*>(
            Vb + (dn * 16 + lm) * 128 + ((lw * 16 + ks * 64) ^ (l7 << 4)));
        oat[0][dn] = __builtin_amdgcn_mfma_f32_16x16x32_bf16(vf, pf[0][ks], oat[0][dn], 0, 0, 0);
        oat[1][dn] = __builtin_amdgcn_mfma_f32_16x16x32_bf16(vf, pf[1][ks], oat[1][dn], 0, 0, 0);
      }
  };

  // prologue: group g stages its tiles #0 (kb=g) and #1 (kb=g+2)
  stage(grp, 0);
  stage(grp + 2, 1);

  for (int i = 0; i < iters; ++i) {
    const int bufidx = i % 3;
    if (i + 1 < iters) asm volatile("s_waitcnt vmcnt(4)" ::: "memory");
    else               asm volatile("s_waitcnt vmcnt(0)" ::: "memory");
    __builtin_amdgcn_s_barrier();
    __builtin_amdgcn_sched_barrier(0);
    if (i + 2 < iters) stage(2 * (i + 2) + grp, (i + 2) % 3);
    const char* Kb = smem + (grp * 3 + bufidx) * 16384;
    const char* Vb = Kb + 8192;
    phase(qf[0], l_acc[0], oacc[0], Kb, Vb);
    if (i < bIters) phase(qf[1], l_acc[1], oacc[1], Kb, Vb);
  }

  // merge group partials: group1 -> LDS (KV region now dead), group0 adds.
  __syncthreads();
  if (grp == 1) {
    char* dst = smem + w4 * 16384 + l * 256;
#pragma unroll
    for (int tq = 0; tq < 2; ++tq)
#pragma unroll
      for (int qm = 0; qm < 2; ++qm)
#pragma unroll
        for (int dn = 0; dn < 4; ++dn)
          *reinterpret_cast<f32x4*>(dst + ((tq * 2 + qm) * 4 + dn) * 16) = oacc[tq][qm][dn];
    float4 lv{l_acc[0][0], l_acc[0][1], l_acc[1][0], l_acc[1][1]};
    *reinterpret_cast<float4*>(smem + 65536 + (w4 * 64 + l) * 16) = lv;
  }
  __syncthreads();
  if (grp == 0) {
    const char* src = smem + w4 * 16384 + l * 256;
#pragma unroll
    for (int tq = 0; tq < 2; ++tq)
#pragma unroll
      for (int qm = 0; qm < 2; ++qm)
#pragma unroll
        for (int dn = 0; dn < 4; ++dn)
          oacc[tq][qm][dn] += *reinterpret_cast<const f32x4*>(src + ((tq * 2 + qm) * 4 + dn) * 16);
    float4 lv = *reinterpret_cast<const float4*>(smem + 65536 + (w4 * 64 + l) * 16);
    l_acc[0][0] += lv.x; l_acc[0][1] += lv.y; l_acc[1][0] += lv.z; l_acc[1][1] += lv.w;

#pragma unroll
    for (int tq = 0; tq < 2; ++tq) {
      const int qb = tq ? qbB : qbA;
#pragma unroll
      for (int qm = 0; qm < 2; ++qm) {
        float ls = (tq ? l_acc[1] : l_acc[0])[qm];
        ls += __shfl_xor(ls, 16);
        ls += __shfl_xor(ls, 32);
        float inv = 1.f / ls;
        const int qg = qb * 128 + w4 * 32 + qm * 16 + lm;
#pragma unroll
        for (int dn = 0; dn < 4; ++dn) {
          f32x4 o = (tq ? oacc[1] : oacc[0])[qm][dn];
          o *= inv;
          ushort_t hh[4], ll[4];
#pragma unroll
          for (int j = 0; j < 4; ++j) {
            hh[j] = f2bf(o[j]);
            ll[j] = f2bf(o[j] - bf2f(hh[j]));
          }
          size_t off = ((size_t)b * SEQ + qg) * DIM + h * HD + dn * 16 + lw * 4;
          uint2 uh{(uint)hh[0] | ((uint)hh[1] << 16), (uint)hh[2] | ((uint)hh[3] << 16)};
          uint2 ul{(uint)ll[0] | ((uint)ll[1] << 16), (uint)ll[2] | ((uint)ll[3] << 16)};
          *reinterpret_cast<uint2*>(&ahi[off]) = uh;
          *reinterpret_cast<uint2*>(&alo[off]) = ul;
        }
      }
    }
  }
}

// ---------------- launch -----------------------------------------------------
extern "C" void kernel_launch(void* const* d_in, const int* in_sizes, int n_in,
                              void* d_out, int out_size, void* d_ws, size_t ws_size,
                              hipStream_t stream) {
  const float* x       = (const float*)d_in[0];
  const float* Wqkv    = (const float*)d_in[1];
  const float* Wout    = (const float*)d_in[2];
  const float* q_scale = (const float*)d_in[3];
  const float* k_scale = (const float*)d_in[4];
  float* out = (float*)d_out;

  char* ws = (char*)d_ws;
  ushort_t* qkv = (ushort_t*)ws;                           // 25.2 MB bf16
  ushort_t* attn_hi = (ushort_t*)ws;                       // reuse qkv region
  ushort_t* attn_lo = attn_hi + (size_t)MROW * DIM;
  size_t off = (size_t)MROW * N3 * 2;
  ushort_t* qT = (ushort_t*)(ws + off); off += (size_t)NB * NH * SEQ * HD * 2;
  ushort_t* kT = (ushort_t*)(ws + off); off += (size_t)NB * NH * SEQ * HD * 2;
  ushort_t* vT = (ushort_t*)(ws + off); off += (size_t)NB * NH * SEQ * HD * 2;
  float* tab   = (float*)(ws + off);    off += (size_t)SEQ * 64 * 4;
  ushort_t* xh  = (ushort_t*)(ws + off); off += (size_t)MROW * DIM * 2;
  ushort_t* wqh = (ushort_t*)(ws + off); off += (size_t)N3 * DIM * 2;
  ushort_t* woh = (ushort_t*)(ws + off); off += (size_t)DIM * DIM * 2;
  ushort_t* wol = (ushort_t*)(ws + off);

  rope_table_kernel<<<dim3(SEQ * 32 / 256), dim3(256), 0, stream>>>(tab);
  cvt_bf16_kernel<<<dim3(MROW * DIM / 4 / 256), dim3(256), 0, stream>>>(x, xh, MROW * DIM / 4);
  cvt_bf16_kernel<<<dim3(N3 * DIM / 4 / 256), dim3(256), 0, stream>>>(Wqkv, wqh, N3 * DIM / 4);
  cvt_split_kernel<<<dim3(DIM * DIM / 4 / 256), dim3(256), 0, stream>>>(Wout, woh, wol, DIM * DIM / 4);
  gemm_mfma_kernel<128, false, true><<<dim3(N3 / 128, MROW / 128), dim3(256), 0, stream>>>(
      xh, nullptr, wqh, nullptr, qkv, N3, DIM);
  qkv_post_kernel<<<dim3(NB * 32 * NH), dim3(256), 0, stream>>>(qkv, q_scale, k_scale, tab, qT, kT, vT);
  attn_mfma_kernel<<<dim3(8, NB * NH), dim3(512), 0, stream>>>(qT, kT, vT, attn_hi, attn_lo);
  gemm_mfma_kernel<128, true, false><<<dim3(DIM / 128, MROW / 128), dim3(256), 0, stream>>>(
      attn_hi, attn_lo, woh, wol, out, DIM, DIM);
}

// Round 8
// 130.620 us; speedup vs baseline: 10.4961x; 1.0166x over previous
//
#include <hip/hip_runtime.h>
#include <hip/hip_bf16.h>
#include <cstddef>

typedef unsigned int uint;
typedef unsigned short ushort_t;
typedef __attribute__((ext_vector_type(8))) short bf16x8;
typedef __attribute__((ext_vector_type(4))) float f32x4;

constexpr int NB   = 2;
constexpr int NP   = 256;
constexpr int DIM  = 1024;
constexpr int NH   = 16;
constexpr int HD   = 64;
constexpr int SEQ  = 2048;
constexpr int MROW = NB * SEQ;      // 4096
constexpr int N3   = 3 * DIM;       // 3072
// softmax in base-2: fold hd^-0.5 * log2(e) into q
constexpr float QS = 0.125f * 1.4426950408889634f;

__device__ __forceinline__ ushort_t f2bf(float x) {
  uint u = __builtin_bit_cast(uint, x);
  u = (u + 0x7fff + ((u >> 16) & 1)) >> 16;   // round-to-nearest-even
  return (ushort_t)u;
}
__device__ __forceinline__ uint pack_bf16(float a, float b) {
  __hip_bfloat162 h = __float22bfloat162_rn(float2{a, b});
  uint u; __builtin_memcpy(&u, &h, 4);        // v_cvt_pk_bf16_f32
  return u;
}
__device__ __forceinline__ float bf2f(ushort_t h) {
  return __builtin_bit_cast(float, (uint)h << 16);
}

__device__ __forceinline__ void gload16(const void* g, void* l) {
  __builtin_amdgcn_global_load_lds((const __attribute__((address_space(1))) uint*)g,
                                   (__attribute__((address_space(3))) uint*)l, 16, 0, 0);
}

// ---------------- K0: RoPE cos/sin table ------------------------------------
__global__ __launch_bounds__(256) void rope_table_kernel(float* __restrict__ tab) {
  int idx = blockIdx.x * 256 + threadIdx.x;
  if (idx >= SEQ * 32) return;
  int l = idx >> 5, i = idx & 31;
  float j = (float)(i & 15);
  float invf = exp2f(-j * (13.287712379549449f / 16.f));
  float pos = (i < 16) ? (float)(l >> 8) : (float)(l & (NP - 1));
  float ang = pos * invf;
  tab[idx]            = cosf(ang);
  tab[SEQ * 32 + idx] = sinf(ang);
}

// ---------------- conversions ------------------------------------------------
__global__ __launch_bounds__(256) void cvt_bf16_kernel(
    const float* __restrict__ s, ushort_t* __restrict__ d, int n4) {
  int i = blockIdx.x * 256 + threadIdx.x;
  if (i >= n4) return;
  float4 v = reinterpret_cast<const float4*>(s)[i];
  uint2 o; o.x = pack_bf16(v.x, v.y); o.y = pack_bf16(v.z, v.w);
  reinterpret_cast<uint2*>(d)[i] = o;
}

__global__ __launch_bounds__(256) void cvt_split_kernel(
    const float* __restrict__ s, ushort_t* __restrict__ hi,
    ushort_t* __restrict__ lo, int n4) {
  int i = blockIdx.x * 256 + threadIdx.x;
  if (i >= n4) return;
  float4 v = reinterpret_cast<const float4*>(s)[i];
  float f[4] = {v.x, v.y, v.z, v.w};
  ushort_t h[4], l[4];
#pragma unroll
  for (int j = 0; j < 4; ++j) {
    h[j] = f2bf(f[j]);
    l[j] = f2bf(f[j] - bf2f(h[j]));
  }
  uint2 oh{(uint)h[0] | ((uint)h[1] << 16), (uint)h[2] | ((uint)h[3] << 16)};
  uint2 ol{(uint)l[0] | ((uint)l[1] << 16), (uint)l[2] | ((uint)l[3] << 16)};
  reinterpret_cast<uint2*>(hi)[i] = oh;
  reinterpret_cast<uint2*>(lo)[i] = ol;
}

// ---------------- bf16 MFMA GEMM: C[M][N] = A[M][K] * B[N][K]^T --------------
// 2-phase double-buffered: stage(t+1) issued BEFORE compute(t); single
// __syncthreads()/iter (its vmcnt(0) drain is exactly the wait for t+1).
template<int BM, bool SPLIT, bool BF16OUT>
__global__ __launch_bounds__(256) void gemm_mfma_kernel(
    const ushort_t* __restrict__ Ah_, const ushort_t* __restrict__ Al_,
    const ushort_t* __restrict__ Bh_, const ushort_t* __restrict__ Bl_,
    void* __restrict__ Cv, int N, int K) {
  constexpr int MF = BM / 32;               // m-frags per wave
  constexpr int REG = (BM + 128) * 128;     // bytes per (A,B) tile pair
  constexpr int PH  = (SPLIT ? 2 : 1) * REG; // bytes per phase
  __shared__ __align__(16) char smem[2 * PH];
  const int tid = threadIdx.x;
  const int l = tid & 63, w4 = tid >> 6;
  const int l7 = l & 7, l3 = l >> 3, lm = l & 15, lw = l >> 4;
  const int wm = w4 >> 1, wn = w4 & 1;
  const int bm = blockIdx.y * BM, bn = blockIdx.x * 128;
  const uint rloc = (uint)(w4 * 8 + l3);
  const uint csrc = (uint)((l7 ^ l3) << 4);
  const uint sw = (uint)(lm & 7);

  f32x4 acc[MF][4] = {};

  auto stageAB = [&](const ushort_t* A_, const ushort_t* B_, int dstoff, int k0) {
    const char* Ab = reinterpret_cast<const char*>(A_);
    const char* Bb = reinterpret_cast<const char*>(B_);
#pragma unroll
    for (int i = 0; i < BM / 32; ++i)
      gload16(Ab + (((size_t)(bm + i * 32 + rloc) * K + k0) << 1) + csrc,
              smem + dstoff + (i * 32 + w4 * 8) * 128);
#pragma unroll
    for (int i = 0; i < 4; ++i)
      gload16(Bb + (((size_t)(bn + i * 32 + rloc) * K + k0) << 1) + csrc,
              smem + dstoff + BM * 128 + (i * 32 + w4 * 8) * 128);
  };

  // prologue: stage tile 0 into phase 0
  stageAB(Ah_, Bh_, 0, 0);
  if constexpr (SPLIT) stageAB(Al_, Bl_, REG, 0);
  __syncthreads();

  int cur = 0;
  for (int k0 = 0; k0 < K; k0 += 64) {
    const int nxt = cur ^ 1;
    if (k0 + 64 < K) {
      stageAB(Ah_, Bh_, nxt * PH, k0 + 64);
      if constexpr (SPLIT) stageAB(Al_, Bl_, nxt * PH + REG, k0 + 64);
    }
    const char* As = smem + cur * PH;
    const char* Bs = As + BM * 128;
    bf16x8 af[MF][2], bfr[4][2];
#pragma unroll
    for (int mi = 0; mi < MF; ++mi)
#pragma unroll
      for (int ks = 0; ks < 2; ++ks)
        af[mi][ks] = *reinterpret_cast<const bf16x8*>(
            As + (wm * (BM / 2) + mi * 16 + lm) * 128 + ((((uint)ks * 4 + lw) ^ sw) << 4));
#pragma unroll
    for (int ni = 0; ni < 4; ++ni)
#pragma unroll
      for (int ks = 0; ks < 2; ++ks)
        bfr[ni][ks] = *reinterpret_cast<const bf16x8*>(
            Bs + (wn * 64 + ni * 16 + lm) * 128 + ((((uint)ks * 4 + lw) ^ sw) << 4));
#pragma unroll
    for (int ks = 0; ks < 2; ++ks)
#pragma unroll
      for (int mi = 0; mi < MF; ++mi)
#pragma unroll
        for (int ni = 0; ni < 4; ++ni)
          acc[mi][ni] = __builtin_amdgcn_mfma_f32_16x16x32_bf16(
              af[mi][ks], bfr[ni][ks], acc[mi][ni], 0, 0, 0);
    if constexpr (SPLIT) {
      const char* As2 = As + REG;
      const char* Bs2 = As2 + BM * 128;
      {  // al * bh   (al freed before bl loads -> lower reg pressure)
        bf16x8 al[MF][2];
#pragma unroll
        for (int mi = 0; mi < MF; ++mi)
#pragma unroll
          for (int ks = 0; ks < 2; ++ks)
            al[mi][ks] = *reinterpret_cast<const bf16x8*>(
                As2 + (wm * (BM / 2) + mi * 16 + lm) * 128 + ((((uint)ks * 4 + lw) ^ sw) << 4));
#pragma unroll
        for (int ks = 0; ks < 2; ++ks)
#pragma unroll
          for (int mi = 0; mi < MF; ++mi)
#pragma unroll
            for (int ni = 0; ni < 4; ++ni)
              acc[mi][ni] = __builtin_amdgcn_mfma_f32_16x16x32_bf16(
                  al[mi][ks], bfr[ni][ks], acc[mi][ni], 0, 0, 0);
      }
      {  // ah * bl
        bf16x8 bl[4][2];
#pragma unroll
        for (int ni = 0; ni < 4; ++ni)
#pragma unroll
          for (int ks = 0; ks < 2; ++ks)
            bl[ni][ks] = *reinterpret_cast<const bf16x8*>(
                Bs2 + (wn * 64 + ni * 16 + lm) * 128 + ((((uint)ks * 4 + lw) ^ sw) << 4));
#pragma unroll
        for (int ks = 0; ks < 2; ++ks)
#pragma unroll
          for (int mi = 0; mi < MF; ++mi)
#pragma unroll
            for (int ni = 0; ni < 4; ++ni)
              acc[mi][ni] = __builtin_amdgcn_mfma_f32_16x16x32_bf16(
                  af[mi][ks], bl[ni][ks], acc[mi][ni], 0, 0, 0);
      }
    }
    __syncthreads();   // drains vmcnt(0): next phase staged; cur readers done
    cur ^= 1;
  }
#pragma unroll
  for (int mi = 0; mi < MF; ++mi)
#pragma unroll
    for (int ni = 0; ni < 4; ++ni) {
      f32x4 a = acc[mi][ni];
      const int row0 = bm + wm * (BM / 2) + mi * 16 + lw * 4;
      const int col  = bn + wn * 64 + ni * 16 + lm;
      if constexpr (BF16OUT) {
        ushort_t* Cb = (ushort_t*)Cv;
#pragma unroll
        for (int r = 0; r < 4; ++r)
          Cb[(size_t)(row0 + r) * N + col] = f2bf(a[r]);
      } else {
        float* Cf = (float*)Cv;
#pragma unroll
        for (int r = 0; r < 4; ++r)
          Cf[(size_t)(row0 + r) * N + col] = a[r];
      }
    }
}

// ---------------- K2: RMSNorm + RoPE (bf16 in); qT/kT row-major, vT d-major --
__global__ __launch_bounds__(256) void qkv_post_kernel(
    const ushort_t* __restrict__ qkv, const float* __restrict__ qs,
    const float* __restrict__ ksc, const float* __restrict__ tab,
    ushort_t* __restrict__ qT, ushort_t* __restrict__ kT, ushort_t* __restrict__ vT) {
  __shared__ ushort_t vt[64][72];
  const int bx = blockIdx.x;
  const int h = bx & 15, lt = (bx >> 4) & 31, b = bx >> 9;
  const int t = threadIdx.x, lr = t >> 2, s = t & 3, d0 = s * 16;
  const int lg = lt * 64 + lr;
  const int bh = b * NH + h;
  const ushort_t* rowp = qkv + ((size_t)(b * SEQ + lg) * N3) + h * HD + d0;

  ushort_t qraw[16], kraw[16], vraw[16];
  *reinterpret_cast<uint4*>(&qraw[0]) = *reinterpret_cast<const uint4*>(rowp);
  *reinterpret_cast<uint4*>(&qraw[8]) = *reinterpret_cast<const uint4*>(rowp + 8);
  *reinterpret_cast<uint4*>(&kraw[0]) = *reinterpret_cast<const uint4*>(rowp + DIM);
  *reinterpret_cast<uint4*>(&kraw[8]) = *reinterpret_cast<const uint4*>(rowp + DIM + 8);
  *reinterpret_cast<uint4*>(&vraw[0]) = *reinterpret_cast<const uint4*>(rowp + 2 * DIM);
  *reinterpret_cast<uint4*>(&vraw[8]) = *reinterpret_cast<const uint4*>(rowp + 2 * DIM + 8);
  float4 qs4[4], ks4[4];
#pragma unroll
  for (int u = 0; u < 4; ++u) {
    qs4[u] = *reinterpret_cast<const float4*>(qs + d0 + u * 4);
    ks4[u] = *reinterpret_cast<const float4*>(ksc + d0 + u * 4);
  }
  const float* sq_ = reinterpret_cast<const float*>(qs4);
  const float* sk_ = reinterpret_cast<const float*>(ks4);
  float vq[16], vk[16];
#pragma unroll
  for (int j = 0; j < 16; ++j) { vq[j] = bf2f(qraw[j]); vk[j] = bf2f(kraw[j]); }

  float sq = 0.f, sk = 0.f;
#pragma unroll
  for (int j = 0; j < 16; ++j) { sq = fmaf(vq[j], vq[j], sq); sk = fmaf(vk[j], vk[j], sk); }
  sq += __shfl_xor(sq, 1); sq += __shfl_xor(sq, 2);
  sk += __shfl_xor(sk, 1); sk += __shfl_xor(sk, 2);
  float rq = rsqrtf(sq * (1.f / HD) + 1e-6f);
  float rk = rsqrtf(sk * (1.f / HD) + 1e-6f);

  float4 c4[2], s4[2];
  const float* tc = tab + (size_t)lg * 32 + s * 8;
  const float* ts = tab + (size_t)SEQ * 32 + (size_t)lg * 32 + s * 8;
  c4[0] = *reinterpret_cast<const float4*>(tc);
  c4[1] = *reinterpret_cast<const float4*>(tc + 4);
  s4[0] = *reinterpret_cast<const float4*>(ts);
  s4[1] = *reinterpret_cast<const float4*>(ts + 4);
  const float* cj = reinterpret_cast<const float*>(c4);
  const float* sj = reinterpret_cast<const float*>(s4);

  uint uq[8], uk[8], uv[8];
#pragma unroll
  for (int j = 0; j < 8; ++j) {
    float qe = vq[2*j] * rq * sq_[2*j], qo = vq[2*j+1] * rq * sq_[2*j+1];
    float ke = vk[2*j] * rk * sk_[2*j], ko = vk[2*j+1] * rk * sk_[2*j+1];
    float c = cj[j], sn = sj[j];
    uq[j] = pack_bf16((qe * c - qo * sn) * QS, (qe * sn + qo * c) * QS);
    uk[j] = pack_bf16(ke * c - ko * sn, ke * sn + ko * c);
    uv[j] = (uint)vraw[2*j] | ((uint)vraw[2*j+1] << 16);
  }
  ushort_t* qp = qT + ((size_t)bh * SEQ + lg) * HD + d0;
  ushort_t* kp = kT + ((size_t)bh * SEQ + lg) * HD + d0;
  reinterpret_cast<uint4*>(qp)[0] = *reinterpret_cast<uint4*>(&uq[0]);
  reinterpret_cast<uint4*>(qp)[1] = *reinterpret_cast<uint4*>(&uq[4]);
  reinterpret_cast<uint4*>(kp)[0] = *reinterpret_cast<uint4*>(&uk[0]);
  reinterpret_cast<uint4*>(kp)[1] = *reinterpret_cast<uint4*>(&uk[4]);
#pragma unroll
  for (int j = 0; j < 16; ++j)
    vt[d0 + j][lr] = (ushort_t)((j & 1) ? (uv[j >> 1] >> 16) : (uv[j >> 1] & 0xffff));
  __syncthreads();
  const int drow = t >> 2, lc = (t & 3) * 16;
  ushort_t* vp = vT + ((size_t)bh * HD + drow) * SEQ + lt * 64 + lc;
  reinterpret_cast<uint4*>(vp)[0] = *reinterpret_cast<const uint4*>(&vt[drow][lc]);
  reinterpret_cast<uint4*>(vp)[1] = *reinterpret_cast<const uint4*>(&vt[drow][lc + 8]);
}

// ---------------- K3: bf16 MFMA block-causal flash attention -----------------
// 8 waves: group0 (waves 0-3) even k-tiles, group1 (waves 4-7) odd k-tiles.
// No-max softmax => k-split partials are exactly additive; merged via LDS.
// Pair-balanced: block p handles q-tiles (15-p, p) = 36 phases = 18 iters.
// K/V fragments hoisted to registers ONCE per iter (shared by both q-tiles);
// P buffer wave-private, reused A-then-B (in-order LDS per wave => safe).
__global__ __launch_bounds__(512) void attn_mfma_kernel(
    const ushort_t* __restrict__ qT, const ushort_t* __restrict__ kT,
    const ushort_t* __restrict__ vT, ushort_t* __restrict__ ahi,
    ushort_t* __restrict__ alo) {
  __shared__ __align__(16) char smem[131072];
  const int tid = threadIdx.x;
  const int l  = tid & 63, w8 = tid >> 6;
  const int grp = w8 >> 2, w4 = w8 & 3;
  const int lm = l & 15, lw = l >> 4, l7 = l & 7, l3 = l >> 3;
  const int bh = blockIdx.y, b = bh >> 4, h = bh & 15;
  const int p = blockIdx.x;
  const int qbA = 15 - p, qbB = p;
  const int nkbA = ((qbA >> 1) + 1) * 4;       // 20..32 (even)
  const int nkbB = ((qbB >> 1) + 1) * 4;       // 4..16  (prefix of A's range)
  const int iters  = nkbA >> 1;
  const int bIters = nkbB >> 1;

  bf16x8 qf[2][2][2];                          // [tile][qm][ks]
#pragma unroll
  for (int tq = 0; tq < 2; ++tq) {
    const size_t qrow0 = (size_t)bh * SEQ + (tq ? qbB : qbA) * 128 + w4 * 32;
#pragma unroll
    for (int qm = 0; qm < 2; ++qm)
#pragma unroll
      for (int ks = 0; ks < 2; ++ks)
        qf[tq][qm][ks] = *reinterpret_cast<const bf16x8*>(
            qT + (qrow0 + qm * 16 + lm) * HD + lw * 8 + ks * 32);
  }

  const char* kTb = reinterpret_cast<const char*>(kT + (size_t)bh * SEQ * HD);
  const char* vTb = reinterpret_cast<const char*>(vT + (size_t)bh * HD * SEQ);
  const uint rloc = w4 * 8 + l3;
  const uint csrc = (uint)((l7 ^ l3) << 4);
  char* Pbase = smem + 98304 + w8 * 4096;

  float l_acc[2][2] = {};
  f32x4 oacc[2][2][4] = {};

  auto stage = [&](int kb, int bufidx) {
    const char* sK = kTb + ((size_t)(kb * 64) + rloc) * 128 + csrc;
    const char* sV = vTb + (size_t)rloc * (SEQ * 2) + (size_t)kb * 128 + csrc;
    char* dK = smem + (grp * 3 + bufidx) * 16384 + w4 * 1024;
    char* dV = dK + 8192;
    gload16(sK, dK);
    gload16(sK + 4096, dK + 4096);
    gload16(sV, dV);
    gload16(sV + (size_t)32 * SEQ * 2, dV + 4096);
  };

  // QK^T into st, using pre-loaded K fragments
  auto qkt = [&](const bf16x8 (&kf)[2][4], const bf16x8 (&qft)[2][2],
                 f32x4 (&st)[2][4]) {
    __builtin_amdgcn_s_setprio(1);
#pragma unroll
    for (int ks = 0; ks < 2; ++ks)
#pragma unroll
      for (int g = 0; g < 4; ++g) {
        st[0][g] = __builtin_amdgcn_mfma_f32_16x16x32_bf16(kf[ks][g], qft[0][ks], st[0][g], 0, 0, 0);
        st[1][g] = __builtin_amdgcn_mfma_f32_16x16x32_bf16(kf[ks][g], qft[1][ks], st[1][g], 0, 0, 0);
      }
    __builtin_amdgcn_s_setprio(0);
  };

  // softmax (no-max, base-2) + P round-trip + PV with pre-loaded V fragments
  auto sm_pv = [&](f32x4 (&st)[2][4], float (&lat)[2], f32x4 (&oat)[2][4],
                   const bf16x8 (&vf)[2][4]) {
#pragma unroll
    for (int qm = 0; qm < 2; ++qm)
#pragma unroll
      for (int g = 0; g < 4; ++g) {
        f32x4 s4 = st[qm][g];
        float p0 = __builtin_amdgcn_exp2f(s4.x);
        float p1 = __builtin_amdgcn_exp2f(s4.y);
        float p2 = __builtin_amdgcn_exp2f(s4.z);
        float p3 = __builtin_amdgcn_exp2f(s4.w);
        lat[qm] += (p0 + p1) + (p2 + p3);
        uint off = (uint)((qm * 16 + lm) * 128 + ((g * 32 + lw * 8) ^ (l7 << 4)));
        *reinterpret_cast<uint*>(Pbase + off)     = pack_bf16(p0, p1);
        *reinterpret_cast<uint*>(Pbase + off + 4) = pack_bf16(p2, p3);
      }
    bf16x8 pf[2][2];
#pragma unroll
    for (int qm = 0; qm < 2; ++qm)
#pragma unroll
      for (int ks = 0; ks < 2; ++ks)
        pf[qm][ks] = *reinterpret_cast<const bf16x8*>(
            Pbase + (qm * 16 + lm) * 128 + ((lw * 16 + ks * 64) ^ (l7 << 4)));
    __builtin_amdgcn_s_setprio(1);
#pragma unroll
    for (int ks = 0; ks < 2; ++ks)
#pragma unroll
      for (int dn = 0; dn < 4; ++dn) {
        oat[0][dn] = __builtin_amdgcn_mfma_f32_16x16x32_bf16(vf[ks][dn], pf[0][ks], oat[0][dn], 0, 0, 0);
        oat[1][dn] = __builtin_amdgcn_mfma_f32_16x16x32_bf16(vf[ks][dn], pf[1][ks], oat[1][dn], 0, 0, 0);
      }
    __builtin_amdgcn_s_setprio(0);
  };

  // prologue: group g stages its tiles #0 (kb=g) and #1 (kb=g+2)
  stage(grp, 0);
  stage(grp + 2, 1);

  for (int i = 0; i < iters; ++i) {
    const int bufidx = i % 3;
    if (i + 1 < iters) asm volatile("s_waitcnt vmcnt(4)" ::: "memory");
    else               asm volatile("s_waitcnt vmcnt(0)" ::: "memory");
    __builtin_amdgcn_s_barrier();
    __builtin_amdgcn_sched_barrier(0);
    if (i + 2 < iters) stage(2 * (i + 2) + grp, (i + 2) % 3);
    const char* Kb = smem + (grp * 3 + bufidx) * 16384;
    const char* Vb = Kb + 8192;

    // K fragments once per iter (shared by both q-tiles)
    bf16x8 kf[2][4];
#pragma unroll
    for (int ks = 0; ks < 2; ++ks)
#pragma unroll
      for (int g = 0; g < 4; ++g)
        kf[ks][g] = *reinterpret_cast<const bf16x8*>(
            Kb + (g * 16 + lm) * 128 + ((lw * 16 + ks * 64) ^ (l7 << 4)));

    f32x4 stA[2][4] = {};
    qkt(kf, qf[0], stA);

    // V fragments once per iter (covers exp/P-turnaround latency)
    bf16x8 vf[2][4];
#pragma unroll
    for (int ks = 0; ks < 2; ++ks)
#pragma unroll
      for (int dn = 0; dn < 4; ++dn)
        vf[ks][dn] = *reinterpret_cast<const bf16x8*>(
            Vb + (dn * 16 + lm) * 128 + ((lw * 16 + ks * 64) ^ (l7 << 4)));

    sm_pv(stA, l_acc[0], oacc[0], vf);

    if (i < bIters) {
      f32x4 stB[2][4] = {};
      qkt(kf, qf[1], stB);
      sm_pv(stB, l_acc[1], oacc[1], vf);
    }
  }

  // merge group partials: group1 -> LDS (KV region now dead), group0 adds.
  // slot-major lane-contiguous 16B layout => conflict-free b128 pattern.
  __syncthreads();
  if (grp == 1) {
#pragma unroll
    for (int tq = 0; tq < 2; ++tq)
#pragma unroll
      for (int qm = 0; qm < 2; ++qm)
#pragma unroll
        for (int dn = 0; dn < 4; ++dn)
          *reinterpret_cast<f32x4*>(
              smem + ((tq * 2 + qm) * 4 + dn) * 4096 + (w4 * 64 + l) * 16) = oacc[tq][qm][dn];
    float4 lv{l_acc[0][0], l_acc[0][1], l_acc[1][0], l_acc[1][1]};
    *reinterpret_cast<float4*>(smem + 65536 + (w4 * 64 + l) * 16) = lv;
  }
  __syncthreads();
  if (grp == 0) {
#pragma unroll
    for (int tq = 0; tq < 2; ++tq)
#pragma unroll
      for (int qm = 0; qm < 2; ++qm)
#pragma unroll
        for (int dn = 0; dn < 4; ++dn)
          oacc[tq][qm][dn] += *reinterpret_cast<const f32x4*>(
              smem + ((tq * 2 + qm) * 4 + dn) * 4096 + (w4 * 64 + l) * 16);
    float4 lv = *reinterpret_cast<const float4*>(smem + 65536 + (w4 * 64 + l) * 16);
    l_acc[0][0] += lv.x; l_acc[0][1] += lv.y; l_acc[1][0] += lv.z; l_acc[1][1] += lv.w;

#pragma unroll
    for (int tq = 0; tq < 2; ++tq) {
      const int qb = tq ? qbB : qbA;
#pragma unroll
      for (int qm = 0; qm < 2; ++qm) {
        float ls = (tq ? l_acc[1] : l_acc[0])[qm];
        ls += __shfl_xor(ls, 16);
        ls += __shfl_xor(ls, 32);
        float inv = 1.f / ls;
        const int qg = qb * 128 + w4 * 32 + qm * 16 + lm;
#pragma unroll
        for (int dn = 0; dn < 4; ++dn) {
          f32x4 o = (tq ? oacc[1] : oacc[0])[qm][dn];
          o *= inv;
          ushort_t hh[4], ll[4];
#pragma unroll
          for (int j = 0; j < 4; ++j) {
            hh[j] = f2bf(o[j]);
            ll[j] = f2bf(o[j] - bf2f(hh[j]));
          }
          size_t off = ((size_t)b * SEQ + qg) * DIM + h * HD + dn * 16 + lw * 4;
          uint2 uh{(uint)hh[0] | ((uint)hh[1] << 16), (uint)hh[2] | ((uint)hh[3] << 16)};
          uint2 ul{(uint)ll[0] | ((uint)ll[1] << 16), (uint)ll[2] | ((uint)ll[3] << 16)};
          *reinterpret_cast<uint2*>(&ahi[off]) = uh;
          *reinterpret_cast<uint2*>(&alo[off]) = ul;
        }
      }
    }
  }
}

// ---------------- launch -----------------------------------------------------
extern "C" void kernel_launch(void* const* d_in, const int* in_sizes, int n_in,
                              void* d_out, int out_size, void* d_ws, size_t ws_size,
                              hipStream_t stream) {
  const float* x       = (const float*)d_in[0];
  const float* Wqkv    = (const float*)d_in[1];
  const float* Wout    = (const float*)d_in[2];
  const float* q_scale = (const float*)d_in[3];
  const float* k_scale = (const float*)d_in[4];
  float* out = (float*)d_out;

  char* ws = (char*)d_ws;
  ushort_t* qkv = (ushort_t*)ws;                           // 25.2 MB bf16
  ushort_t* attn_hi = (ushort_t*)ws;                       // reuse qkv region
  ushort_t* attn_lo = attn_hi + (size_t)MROW * DIM;
  size_t off = (size_t)MROW * N3 * 2;
  ushort_t* qT = (ushort_t*)(ws + off); off += (size_t)NB * NH * SEQ * HD * 2;
  ushort_t* kT = (ushort_t*)(ws + off); off += (size_t)NB * NH * SEQ * HD * 2;
  ushort_t* vT = (ushort_t*)(ws + off); off += (size_t)NB * NH * SEQ * HD * 2;
  float* tab   = (float*)(ws + off);    off += (size_t)SEQ * 64 * 4;
  ushort_t* xh  = (ushort_t*)(ws + off); off += (size_t)MROW * DIM * 2;
  ushort_t* wqh = (ushort_t*)(ws + off); off += (size_t)N3 * DIM * 2;
  ushort_t* woh = (ushort_t*)(ws + off); off += (size_t)DIM * DIM * 2;
  ushort_t* wol = (ushort_t*)(ws + off);

  rope_table_kernel<<<dim3(SEQ * 32 / 256), dim3(256), 0, stream>>>(tab);
  cvt_bf16_kernel<<<dim3(MROW * DIM / 4 / 256), dim3(256), 0, stream>>>(x, xh, MROW * DIM / 4);
  cvt_bf16_kernel<<<dim3(N3 * DIM / 4 / 256), dim3(256), 0, stream>>>(Wqkv, wqh, N3 * DIM / 4);
  cvt_split_kernel<<<dim3(DIM * DIM / 4 / 256), dim3(256), 0, stream>>>(Wout, woh, wol, DIM * DIM / 4);
  gemm_mfma_kernel<128, false, true><<<dim3(N3 / 128, MROW / 128), dim3(256), 0, stream>>>(
      xh, nullptr, wqh, nullptr, qkv, N3, DIM);
  qkv_post_kernel<<<dim3(NB * 32 * NH), dim3(256), 0, stream>>>(qkv, q_scale, k_scale, tab, qT, kT, vT);
  attn_mfma_kernel<<<dim3(8, NB * NH), dim3(512), 0, stream>>>(qT, kT, vT, attn_hi, attn_lo);
  gemm_mfma_kernel<128, true, false><<<dim3(DIM / 128, MROW / 128), dim3(256), 0, stream>>>(
      attn_hi, attn_lo, woh, wol, out, DIM, DIM);
}